// Round 1
// baseline (443.229 us; speedup 1.0000x reference)
//
#include <hip/hip_runtime.h>

// ---------------- problem constants ----------------
#define NBATCH 4
#define SEQ    4096
#define DMODEL 512
#define NHEAD  8
#define HDIM   64
#define NSN    32
#define NXT    2048
#define QLEN   2080   // NXT + NSN
#define KLEN   4128   // SEQ + NSN
#define KPAD   72     // LDS row stride (72*2 = 144 B = 9*16B -> b128-aligned, bank-spread)

using bf16x8 = __attribute__((ext_vector_type(8))) short;
using f32x4  = __attribute__((ext_vector_type(4))) float;

typedef __attribute__((address_space(1))) unsigned int gu32;
typedef __attribute__((address_space(3))) unsigned int lu32;

__device__ __forceinline__ unsigned short f2bf(float f) {
  unsigned int u = __float_as_uint(f);
  u += 0x7FFF + ((u >> 16) & 1);          // RTNE
  return (unsigned short)(u >> 16);
}

__device__ __forceinline__ f32x4 mfma16(bf16x8 a, bf16x8 b, f32x4 c) {
  return __builtin_amdgcn_mfma_f32_16x16x32_bf16(a, b, c, 0, 0, 0);
}

__device__ __forceinline__ void gload_lds16(const void* g, void* lds_base) {
  // HW writes lane l's 16B at lds_base + l*16 (wave-uniform base, per-lane global addr)
  __builtin_amdgcn_global_load_lds((const gu32*)g, (lu32*)lds_base, 16, 0, 0);
}

// ---------------- fp32 -> bf16 converts ----------------
__global__ __launch_bounds__(256) void cvt_f32_bf16_v4(const float* __restrict__ src,
                                                       unsigned short* __restrict__ dst, int n4) {
  int i = blockIdx.x * 256 + threadIdx.x;
  if (i >= n4) return;
  float4 v = reinterpret_cast<const float4*>(src)[i];
  ushort4 r;
  r.x = f2bf(v.x); r.y = f2bf(v.y); r.z = f2bf(v.z); r.w = f2bf(v.w);
  reinterpret_cast<ushort4*>(dst)[i] = r;
}

__global__ __launch_bounds__(256) void cvt_w4(const float* __restrict__ a, const float* __restrict__ b,
                                              const float* __restrict__ c, const float* __restrict__ d,
                                              unsigned short* __restrict__ dst) {
  const float* s = blockIdx.y == 0 ? a : blockIdx.y == 1 ? b : blockIdx.y == 2 ? c : d;
  int i = blockIdx.x * 256 + threadIdx.x;   // 65536 float4 per matrix
  float4 v = reinterpret_cast<const float4*>(s)[i];
  ushort4 r;
  r.x = f2bf(v.x); r.y = f2bf(v.y); r.z = f2bf(v.z); r.w = f2bf(v.w);
  reinterpret_cast<ushort4*>(dst)[(size_t)blockIdx.y * 65536 + i] = r;
}

// ---------------- seq projection GEMM: C[M][512] = X[M][512] @ W[512][512]^T ----------------
// X rows map through (b, row_off): xrow = (gr>>rpb_shift)*4096 + row_off + (gr & mask)
// Out written bf16 head-split: Out[((b*8+h)*out_L + i)*64 + d], h=o>>6, d=o&63
__global__ __launch_bounds__(256) void proj_gemm(const unsigned short* __restrict__ X,
                                                 const unsigned short* __restrict__ W,
                                                 unsigned short* __restrict__ Out,
                                                 int rpb_shift, int row_off, int out_L, float scale) {
  __shared__ unsigned short As[128 * 32];
  __shared__ unsigned short Bs[128 * 32];
  const int tid = threadIdx.x;
  const int w = tid >> 6, l = tid & 63;
  const int lg = l >> 4, lr = l & 15;
  const int row0 = blockIdx.x * 128, col0 = blockIdx.y * 128;
  const int wr = (w >> 1) * 64, wc = (w & 1) * 64;
  const int mask = (1 << rpb_shift) - 1;

  f32x4 acc[4][4];
#pragma unroll
  for (int m = 0; m < 4; ++m)
#pragma unroll
    for (int n = 0; n < 4; ++n) acc[m][n] = (f32x4){0.f, 0.f, 0.f, 0.f};

  const int sr = w * 16 + (l >> 2);   // staged row within tile (+ i*64)
  const int sc = (l & 3) * 8;         // staged col (bf16 elems)

  for (int k0 = 0; k0 < 512; k0 += 32) {
#pragma unroll
    for (int i = 0; i < 2; ++i) {
      int gr = row0 + sr + i * 64;
      int xrow = ((gr >> rpb_shift) << 12) + row_off + (gr & mask);
      const unsigned short* gpa = X + (size_t)xrow * 512 + k0 + sc;
      gload_lds16(gpa, (char*)As + i * 4096 + w * 1024);
      const unsigned short* gpb = W + (size_t)(col0 + sr + i * 64) * 512 + k0 + sc;
      gload_lds16(gpb, (char*)Bs + i * 4096 + w * 1024);
    }
    __syncthreads();
    bf16x8 av[4], bv[4];
#pragma unroll
    for (int m = 0; m < 4; ++m) av[m] = *(const bf16x8*)&As[(wr + m * 16 + lr) * 32 + lg * 8];
#pragma unroll
    for (int n = 0; n < 4; ++n) bv[n] = *(const bf16x8*)&Bs[(wc + n * 16 + lr) * 32 + lg * 8];
#pragma unroll
    for (int m = 0; m < 4; ++m)
#pragma unroll
      for (int n = 0; n < 4; ++n) acc[m][n] = mfma16(av[m], bv[n], acc[m][n]);
    __syncthreads();
  }

#pragma unroll
  for (int m = 0; m < 4; ++m) {
    int crow = row0 + wr + m * 16 + lg * 4;
#pragma unroll
    for (int n = 0; n < 4; ++n) {
      int ccol = col0 + wc + n * 16 + lr;
      int hh = ccol >> 6, dd = ccol & 63;
#pragma unroll
      for (int r = 0; r < 4; ++r) {
        int cr = crow + r;
        int bb = cr >> rpb_shift, ii = cr & mask;
        Out[(((size_t)bb * NHEAD + hh) * out_L + ii) * HDIM + dd] = f2bf(acc[m][n][r] * scale);
      }
    }
  }
}

// ---------------- ns projections: out[b,n,o] = sum_d x[b,n,d] * W[n,d,o] ----------------
// grid (4 o-chunks of 128, 32 n, 3 proj)
__global__ __launch_bounds__(256) void ns_proj(const float* __restrict__ nst,
                                               const float* __restrict__ Wnq, const float* __restrict__ Wnk,
                                               const float* __restrict__ Wnv,
                                               unsigned short* __restrict__ Qb, unsigned short* __restrict__ Kb,
                                               unsigned short* __restrict__ Vb) {
  const int oc = blockIdx.x, n = blockIdx.y, p = blockIdx.z;
  const float* W = p == 0 ? Wnq : p == 1 ? Wnk : Wnv;
  unsigned short* Out = p == 0 ? Qb : p == 1 ? Kb : Vb;
  const int out_L = p == 0 ? QLEN : KLEN;
  const int orow = p == 0 ? NXT + n : SEQ + n;
  const float scale = p == 0 ? 0.125f : 1.f;

  __shared__ float xs[NBATCH][DMODEL];
  __shared__ float red[NBATCH][128];
  const int tid = threadIdx.x;
  for (int idx = tid; idx < NBATCH * DMODEL; idx += 256)
    xs[idx >> 9][idx & 511] = nst[(size_t)((idx >> 9) * NSN + n) * DMODEL + (idx & 511)];
  __syncthreads();

  const int o = oc * 128 + (tid & 127);
  const int dh = tid >> 7;
  float a0 = 0.f, a1 = 0.f, a2 = 0.f, a3 = 0.f;
  const float* wp = W + (size_t)n * DMODEL * DMODEL + o;
#pragma unroll 8
  for (int d = dh * 256; d < dh * 256 + 256; ++d) {
    float wv = wp[(size_t)d * DMODEL];
    a0 += xs[0][d] * wv; a1 += xs[1][d] * wv; a2 += xs[2][d] * wv; a3 += xs[3][d] * wv;
  }
  if (dh == 1) { red[0][tid & 127] = a0; red[1][tid & 127] = a1; red[2][tid & 127] = a2; red[3][tid & 127] = a3; }
  __syncthreads();
  if (dh == 0) {
    a0 += red[0][tid & 127]; a1 += red[1][tid & 127]; a2 += red[2][tid & 127]; a3 += red[3][tid & 127];
    int hh = o >> 6, dd = o & 63;
    float v[4] = {a0, a1, a2, a3};
#pragma unroll
    for (int b = 0; b < NBATCH; ++b)
      Out[(((size_t)b * NHEAD + hh) * out_L + orow) * HDIM + dd] = f2bf(v[b] * scale);
  }
}

// ---------------- flash attention ----------------
// grid (33 qblocks, 8 heads, 4 batch); 4 waves, wave w owns q rows q0+w*16..+15
__global__ __launch_bounds__(256) void attn_kernel(const unsigned short* __restrict__ Qb,
                                                   const unsigned short* __restrict__ Kb,
                                                   const unsigned short* __restrict__ Vb,
                                                   unsigned short* __restrict__ Att) {
  __shared__ unsigned short Ks[64 * KPAD];
  __shared__ unsigned short Vt[64 * KPAD];          // Vt[d][kv]
  __shared__ unsigned short Ps[4][16 * KPAD];       // per-wave P

  const int tid = threadIdx.x;
  const int w = tid >> 6, l = tid & 63;
  const int lg = l >> 4, lr = l & 15;
  const int qb = (int)gridDim.x - 1 - (int)blockIdx.x;   // big blocks first
  const int h = blockIdx.y, b = blockIdx.z;
  const int q0 = qb * 64;
  const int base = NXT + q0;
  const int nkb = (base >> 6) + 1;

  const unsigned short* Qh = Qb + ((size_t)(b * NHEAD + h)) * QLEN * HDIM;
  const unsigned short* Kh = Kb + ((size_t)(b * NHEAD + h)) * KLEN * HDIM;
  const unsigned short* Vh = Vb + ((size_t)(b * NHEAD + h)) * KLEN * HDIM;

  int qrow = q0 + w * 16 + lr;
  int qrc = qrow < QLEN - 1 ? qrow : QLEN - 1;
  bf16x8 qa[2];
  qa[0] = *reinterpret_cast<const bf16x8*>(Qh + (size_t)qrc * HDIM + lg * 8);
  qa[1] = *reinterpret_cast<const bf16x8*>(Qh + (size_t)qrc * HDIM + 32 + lg * 8);

  f32x4 acc[4];
#pragma unroll
  for (int n = 0; n < 4; ++n) acc[n] = (f32x4){0.f, 0.f, 0.f, 0.f};
  float m_old[4], lsum[4];
#pragma unroll
  for (int r = 0; r < 4; ++r) { m_old[r] = -1e30f; lsum[r] = 0.f; }

  for (int kb = 0; kb < nkb; ++kb) {
    const int kv0 = kb * 64;
    __syncthreads();   // previous iteration's LDS reads done
    // stage K (row-major, padded) and V (transposed, padded)
#pragma unroll
    for (int i = 0; i < 2; ++i) {
      int c = i * 256 + tid;                 // 0..511 chunks of 16B
      int row = c >> 3, d0 = (c & 7) * 8;
      int kvg = kv0 + row; kvg = kvg < KLEN - 1 ? kvg : KLEN - 1;
      int4 kv4 = *reinterpret_cast<const int4*>(Kh + (size_t)kvg * HDIM + d0);
      *reinterpret_cast<int4*>(&Ks[row * KPAD + d0]) = kv4;
      int4 vv4 = *reinterpret_cast<const int4*>(Vh + (size_t)kvg * HDIM + d0);
      const unsigned short* pv = reinterpret_cast<const unsigned short*>(&vv4);
#pragma unroll
      for (int j = 0; j < 8; ++j) Vt[(d0 + j) * KPAD + row] = pv[j];
    }
    __syncthreads();

    // S = Q K^T  (16 q-rows x 64 keys per wave)
    f32x4 s[4];
#pragma unroll
    for (int n = 0; n < 4; ++n) s[n] = (f32x4){0.f, 0.f, 0.f, 0.f};
#pragma unroll
    for (int n = 0; n < 4; ++n) {
      bf16x8 k0f = *(const bf16x8*)&Ks[(n * 16 + lr) * KPAD + lg * 8];
      bf16x8 k1f = *(const bf16x8*)&Ks[(n * 16 + lr) * KPAD + 32 + lg * 8];
      s[n] = mfma16(qa[0], k0f, s[n]);
      s[n] = mfma16(qa[1], k1f, s[n]);
    }

    if (kb == nkb - 1) {   // diagonal block: mask kv0+col > base+row
#pragma unroll
      for (int n = 0; n < 4; ++n) {
        int colc = n * 16 + lr;
#pragma unroll
        for (int r = 0; r < 4; ++r) {
          int rowr = w * 16 + lg * 4 + r;
          if (colc > rowr) s[n][r] = -1e30f;
        }
      }
    }

    // online softmax (rows live on 16-lane groups)
    float p[4][4];
#pragma unroll
    for (int r = 0; r < 4; ++r) {
      float v = fmaxf(fmaxf(s[0][r], s[1][r]), fmaxf(s[2][r], s[3][r]));
      v = fmaxf(v, __shfl_xor(v, 1)); v = fmaxf(v, __shfl_xor(v, 2));
      v = fmaxf(v, __shfl_xor(v, 4)); v = fmaxf(v, __shfl_xor(v, 8));
      float mn = fmaxf(m_old[r], v);
      float sc = __expf(m_old[r] - mn);
      float sum = 0.f;
#pragma unroll
      for (int n = 0; n < 4; ++n) { p[n][r] = __expf(s[n][r] - mn); sum += p[n][r]; }
      sum += __shfl_xor(sum, 1); sum += __shfl_xor(sum, 2);
      sum += __shfl_xor(sum, 4); sum += __shfl_xor(sum, 8);
      lsum[r] = lsum[r] * sc + sum;
#pragma unroll
      for (int n = 0; n < 4; ++n) acc[n][r] *= sc;
      m_old[r] = mn;
    }

    // P -> LDS (bf16), then PV
#pragma unroll
    for (int n = 0; n < 4; ++n)
#pragma unroll
      for (int r = 0; r < 4; ++r)
        Ps[w][(lg * 4 + r) * KPAD + n * 16 + lr] = f2bf(p[n][r]);
    asm volatile("s_waitcnt lgkmcnt(0)" ::: "memory");

    bf16x8 pa0 = *(const bf16x8*)&Ps[w][lr * KPAD + lg * 8];
    bf16x8 pa1 = *(const bf16x8*)&Ps[w][lr * KPAD + 32 + lg * 8];
#pragma unroll
    for (int n = 0; n < 4; ++n) {
      bf16x8 v0 = *(const bf16x8*)&Vt[(n * 16 + lr) * KPAD + lg * 8];
      bf16x8 v1 = *(const bf16x8*)&Vt[(n * 16 + lr) * KPAD + 32 + lg * 8];
      acc[n] = mfma16(pa0, v0, acc[n]);
      acc[n] = mfma16(pa1, v1, acc[n]);
    }
  }

  // finalize + store att (bf16) at [b][qi][h*64 + d]
  float inv[4];
#pragma unroll
  for (int r = 0; r < 4; ++r) inv[r] = 1.f / lsum[r];
#pragma unroll
  for (int n = 0; n < 4; ++n)
#pragma unroll
    for (int r = 0; r < 4; ++r) {
      int qi = q0 + w * 16 + lg * 4 + r;
      if (qi < QLEN)
        Att[((size_t)b * QLEN + qi) * DMODEL + h * HDIM + n * 16 + lr] = f2bf(acc[n][r] * inv[r]);
    }
}

// ---------------- output GEMM: out = att @ Wo^T, split store ----------------
__global__ __launch_bounds__(256) void out_gemm(const unsigned short* __restrict__ A,
                                                const unsigned short* __restrict__ W,
                                                float* __restrict__ Out) {
  __shared__ unsigned short As[128 * 32];
  __shared__ unsigned short Bs[128 * 32];
  const int tid = threadIdx.x;
  const int w = tid >> 6, l = tid & 63;
  const int lg = l >> 4, lr = l & 15;
  const int row0 = blockIdx.x * 128, col0 = blockIdx.y * 128;
  const int wr = (w >> 1) * 64, wc = (w & 1) * 64;

  f32x4 acc[4][4];
#pragma unroll
  for (int m = 0; m < 4; ++m)
#pragma unroll
    for (int n = 0; n < 4; ++n) acc[m][n] = (f32x4){0.f, 0.f, 0.f, 0.f};

  const int sr = w * 16 + (l >> 2);
  const int sc = (l & 3) * 8;

  for (int k0 = 0; k0 < 512; k0 += 32) {
#pragma unroll
    for (int i = 0; i < 2; ++i) {
      const unsigned short* gpa = A + (size_t)(row0 + sr + i * 64) * 512 + k0 + sc;
      gload_lds16(gpa, (char*)As + i * 4096 + w * 1024);
      const unsigned short* gpb = W + (size_t)(col0 + sr + i * 64) * 512 + k0 + sc;
      gload_lds16(gpb, (char*)Bs + i * 4096 + w * 1024);
    }
    __syncthreads();
    bf16x8 av[4], bv[4];
#pragma unroll
    for (int m = 0; m < 4; ++m) av[m] = *(const bf16x8*)&As[(wr + m * 16 + lr) * 32 + lg * 8];
#pragma unroll
    for (int n = 0; n < 4; ++n) bv[n] = *(const bf16x8*)&Bs[(wc + n * 16 + lr) * 32 + lg * 8];
#pragma unroll
    for (int m = 0; m < 4; ++m)
#pragma unroll
      for (int n = 0; n < 4; ++n) acc[m][n] = mfma16(av[m], bv[n], acc[m][n]);
    __syncthreads();
  }

#pragma unroll
  for (int m = 0; m < 4; ++m) {
    int crow = row0 + wr + m * 16 + lg * 4;
#pragma unroll
    for (int n = 0; n < 4; ++n) {
      int ccol = col0 + wc + n * 16 + lr;
#pragma unroll
      for (int r = 0; r < 4; ++r) {
        int cr = crow + r;
        int bb = cr / QLEN, ii = cr - bb * QLEN;
        size_t off = ii < NXT
                       ? ((size_t)bb * NXT + ii) * DMODEL + ccol
                       : (size_t)NBATCH * NXT * DMODEL + ((size_t)bb * NSN + (ii - NXT)) * DMODEL + ccol;
        Out[off] = acc[m][n][r];
      }
    }
  }
}

// ---------------- host launch ----------------
extern "C" void kernel_launch(void* const* d_in, const int* in_sizes, int n_in,
                              void* d_out, int out_size, void* d_ws, size_t ws_size,
                              hipStream_t stream) {
  const float* seq = (const float*)d_in[0];
  const float* nst = (const float*)d_in[2];
  const float* Wq  = (const float*)d_in[5];
  const float* Wk  = (const float*)d_in[6];
  const float* Wv  = (const float*)d_in[7];
  const float* nsq = (const float*)d_in[8];
  const float* nsk = (const float*)d_in[9];
  const float* nsv = (const float*)d_in[10];
  const float* Wo  = (const float*)d_in[11];
  float* out = (float*)d_out;

  char* ws = (char*)d_ws;
  unsigned short* Xbf  = (unsigned short*)(ws);                       // 16 MB
  unsigned short* Wqb  = (unsigned short*)(ws + 16777216);            // 4x 512KB
  unsigned short* Wkb  = Wqb + 262144;
  unsigned short* Wvb  = Wkb + 262144;
  unsigned short* Wob  = Wvb + 262144;
  unsigned short* Qbuf = (unsigned short*)(ws + 18874368);            // 8.5 MB
  unsigned short* Kbuf = (unsigned short*)(ws + 27394048);            // 16.9 MB
  unsigned short* Vbuf = (unsigned short*)(ws + 44302336);            // 16.9 MB
  unsigned short* Att  = (unsigned short*)(ws + 61210624);            // 8.5 MB
  if (ws_size < 69730304) return;   // insufficient scratch -> leave output poisoned (visible failure)

  cvt_f32_bf16_v4<<<dim3(8192), dim3(256), 0, stream>>>(seq, Xbf, 2097152);
  cvt_w4<<<dim3(256, 4), dim3(256), 0, stream>>>(Wq, Wk, Wv, Wo, Wqb);
  proj_gemm<<<dim3(128, 4), dim3(256), 0, stream>>>(Xbf, Wkb, Kbuf, 12, 0, KLEN, 1.f);
  proj_gemm<<<dim3(128, 4), dim3(256), 0, stream>>>(Xbf, Wvb, Vbuf, 12, 0, KLEN, 1.f);
  proj_gemm<<<dim3(64, 4), dim3(256), 0, stream>>>(Xbf, Wqb, Qbuf, 11, 2048, QLEN, 0.125f);
  ns_proj<<<dim3(4, 32, 3), dim3(256), 0, stream>>>(nst, nsq, nsk, nsv, Qbuf, Kbuf, Vbuf);
  attn_kernel<<<dim3(33, 8, 4), dim3(256), 0, stream>>>(Qbuf, Kbuf, Vbuf, Att);
  out_gemm<<<dim3(65, 4), dim3(256), 0, stream>>>(Att, Wob, out);
}

// Round 3
// 440.173 us; speedup vs baseline: 1.0069x; 1.0069x over previous
//
#include <hip/hip_runtime.h>

// ---------------- problem constants ----------------
#define NBATCH 4
#define SEQ    4096
#define DMODEL 512
#define NHEAD  8
#define HDIM   64
#define NSN    32
#define NXT    2048
#define QLEN   2080   // NXT + NSN
#define KLEN   4128   // SEQ + NSN

// attention tile geometry
#define KVB 128       // keys per LDS tile
#define KP  72        // Ks row stride (elems): 144B, 16B-aligned
#define VP  136       // Vs row stride
#define PP  136       // Ps row stride

using bf16x8 = __attribute__((ext_vector_type(8))) short;
using f32x4  = __attribute__((ext_vector_type(4))) float;

typedef __attribute__((address_space(1))) unsigned int gu32;
typedef __attribute__((address_space(3))) unsigned int lu32;

__device__ __forceinline__ unsigned short f2bf(float f) {
  unsigned int u = __float_as_uint(f);
  u += 0x7FFF + ((u >> 16) & 1);          // RTNE
  return (unsigned short)(u >> 16);
}

__device__ __forceinline__ f32x4 mfma16(bf16x8 a, bf16x8 b, f32x4 c) {
  return __builtin_amdgcn_mfma_f32_16x16x32_bf16(a, b, c, 0, 0, 0);
}

__device__ __forceinline__ void gload_lds16(const void* g, void* lds_base) {
  __builtin_amdgcn_global_load_lds((const gu32*)g, (lu32*)lds_base, 16, 0, 0);
}

// ---------------- fp32 -> bf16 converts ----------------
__global__ __launch_bounds__(256) void cvt_f32_bf16_v4(const float* __restrict__ src,
                                                       unsigned short* __restrict__ dst, int n4) {
  int i = blockIdx.x * 256 + threadIdx.x;
  if (i >= n4) return;
  float4 v = reinterpret_cast<const float4*>(src)[i];
  ushort4 r;
  r.x = f2bf(v.x); r.y = f2bf(v.y); r.z = f2bf(v.z); r.w = f2bf(v.w);
  reinterpret_cast<ushort4*>(dst)[i] = r;
}

__global__ __launch_bounds__(256) void cvt_w4(const float* __restrict__ a, const float* __restrict__ b,
                                              const float* __restrict__ c, const float* __restrict__ d,
                                              unsigned short* __restrict__ dst) {
  const float* s = blockIdx.y == 0 ? a : blockIdx.y == 1 ? b : blockIdx.y == 2 ? c : d;
  int i = blockIdx.x * 256 + threadIdx.x;   // 65536 float4 per matrix
  float4 v = reinterpret_cast<const float4*>(s)[i];
  ushort4 r;
  r.x = f2bf(v.x); r.y = f2bf(v.y); r.z = f2bf(v.z); r.w = f2bf(v.w);
  reinterpret_cast<ushort4*>(dst)[(size_t)blockIdx.y * 65536 + i] = r;
}

// ---------------- seq projection GEMM (m97 structure, known-good) ----------------
__global__ __launch_bounds__(256) void proj_gemm(const unsigned short* __restrict__ X,
                                                 const unsigned short* __restrict__ W,
                                                 unsigned short* __restrict__ Out,
                                                 int rpb_shift, int row_off, int out_L, float scale) {
  __shared__ unsigned short As[128 * 32];
  __shared__ unsigned short Bs[128 * 32];
  const int tid = threadIdx.x;
  const int w = tid >> 6, l = tid & 63;
  const int lg = l >> 4, lr = l & 15;
  const int row0 = blockIdx.x * 128, col0 = blockIdx.y * 128;
  const int wr = (w >> 1) * 64, wc = (w & 1) * 64;
  const int mask = (1 << rpb_shift) - 1;

  f32x4 acc[4][4];
#pragma unroll
  for (int m = 0; m < 4; ++m)
#pragma unroll
    for (int n = 0; n < 4; ++n) acc[m][n] = (f32x4){0.f, 0.f, 0.f, 0.f};

  const int sr = w * 16 + (l >> 2);
  const int sc = (l & 3) * 8;

  for (int k0 = 0; k0 < 512; k0 += 32) {
#pragma unroll
    for (int i = 0; i < 2; ++i) {
      int gr = row0 + sr + i * 64;
      int xrow = ((gr >> rpb_shift) << 12) + row_off + (gr & mask);
      const unsigned short* gpa = X + (size_t)xrow * 512 + k0 + sc;
      gload_lds16(gpa, (char*)As + i * 4096 + w * 1024);
      const unsigned short* gpb = W + (size_t)(col0 + sr + i * 64) * 512 + k0 + sc;
      gload_lds16(gpb, (char*)Bs + i * 4096 + w * 1024);
    }
    __syncthreads();
    bf16x8 av[4], bv[4];
#pragma unroll
    for (int m = 0; m < 4; ++m) av[m] = *(const bf16x8*)&As[(wr + m * 16 + lr) * 32 + lg * 8];
#pragma unroll
    for (int n = 0; n < 4; ++n) bv[n] = *(const bf16x8*)&Bs[(wc + n * 16 + lr) * 32 + lg * 8];
#pragma unroll
    for (int m = 0; m < 4; ++m)
#pragma unroll
      for (int n = 0; n < 4; ++n) acc[m][n] = mfma16(av[m], bv[n], acc[m][n]);
    __syncthreads();
  }

#pragma unroll
  for (int m = 0; m < 4; ++m) {
    int crow = row0 + wr + m * 16 + lg * 4;
#pragma unroll
    for (int n = 0; n < 4; ++n) {
      int ccol = col0 + wc + n * 16 + lr;
      int hh = ccol >> 6, dd = ccol & 63;
#pragma unroll
      for (int r = 0; r < 4; ++r) {
        int cr = crow + r;
        int bb = cr >> rpb_shift, ii = cr & mask;
        Out[(((size_t)bb * NHEAD + hh) * out_L + ii) * HDIM + dd] = f2bf(acc[m][n][r] * scale);
      }
    }
  }
}

// ---------------- ns projections (unchanged) ----------------
__global__ __launch_bounds__(256) void ns_proj(const float* __restrict__ nst,
                                               const float* __restrict__ Wnq, const float* __restrict__ Wnk,
                                               const float* __restrict__ Wnv,
                                               unsigned short* __restrict__ Qb, unsigned short* __restrict__ Kb,
                                               unsigned short* __restrict__ Vb) {
  const int oc = blockIdx.x, n = blockIdx.y, p = blockIdx.z;
  const float* W = p == 0 ? Wnq : p == 1 ? Wnk : Wnv;
  unsigned short* Out = p == 0 ? Qb : p == 1 ? Kb : Vb;
  const int out_L = p == 0 ? QLEN : KLEN;
  const int orow = p == 0 ? NXT + n : SEQ + n;
  const float scale = p == 0 ? 0.125f : 1.f;

  __shared__ float xs[NBATCH][DMODEL];
  __shared__ float red[NBATCH][128];
  const int tid = threadIdx.x;
  for (int idx = tid; idx < NBATCH * DMODEL; idx += 256)
    xs[idx >> 9][idx & 511] = nst[(size_t)((idx >> 9) * NSN + n) * DMODEL + (idx & 511)];
  __syncthreads();

  const int o = oc * 128 + (tid & 127);
  const int dh = tid >> 7;
  float a0 = 0.f, a1 = 0.f, a2 = 0.f, a3 = 0.f;
  const float* wp = W + (size_t)n * DMODEL * DMODEL + o;
#pragma unroll 8
  for (int d = dh * 256; d < dh * 256 + 256; ++d) {
    float wv = wp[(size_t)d * DMODEL];
    a0 += xs[0][d] * wv; a1 += xs[1][d] * wv; a2 += xs[2][d] * wv; a3 += xs[3][d] * wv;
  }
  if (dh == 1) { red[0][tid & 127] = a0; red[1][tid & 127] = a1; red[2][tid & 127] = a2; red[3][tid & 127] = a3; }
  __syncthreads();
  if (dh == 0) {
    a0 += red[0][tid & 127]; a1 += red[1][tid & 127]; a2 += red[2][tid & 127]; a3 += red[3][tid & 127];
    int hh = o >> 6, dd = o & 63;
    float v[4] = {a0, a1, a2, a3};
#pragma unroll
    for (int b = 0; b < NBATCH; ++b)
      Out[(((size_t)b * NHEAD + hh) * out_L + orow) * HDIM + dd] = f2bf(v[b] * scale);
  }
}

// ---------------- global V transpose: Vt[bh][d][kv] = V[bh][kv][d] ----------------
__global__ __launch_bounds__(256) void vtrans(const unsigned short* __restrict__ V,
                                              unsigned short* __restrict__ Vt) {
  __shared__ unsigned short t[64 * 64];
  const int tid = threadIdx.x;
  const int kv0 = blockIdx.x * 64, bh = blockIdx.y;
  const unsigned short* Vhp = V + (size_t)bh * KLEN * HDIM;
  unsigned short* Vtp = Vt + (size_t)bh * HDIM * KLEN;

#pragma unroll
  for (int i = 0; i < 2; ++i) {
    int c = i * 256 + tid;             // 512 chunks of 16B: row = kv-local, c8 = d-chunk
    int row = c >> 3, c8 = c & 7;
    int kvg = kv0 + row; if (kvg > KLEN - 1) kvg = KLEN - 1;
    int4 v4 = *(const int4*)(Vhp + (size_t)kvg * HDIM + c8 * 8);
    *(int4*)&t[row * 64 + ((c8 ^ ((row >> 3) & 7)) * 8)] = v4;
  }
  __syncthreads();
#pragma unroll
  for (int i = 0; i < 2; ++i) {
    int c = i * 256 + tid;             // 512: d row, k8 = kv-chunk
    int d = c >> 3, k8 = c & 7;
    if (kv0 + k8 * 8 <= KLEN - 8) {
      unsigned int wd[4];
#pragma unroll
      for (int jj = 0; jj < 4; ++jj) {
        int ka = k8 * 8 + jj * 2, kb2 = ka + 1;
        unsigned int lo = t[ka  * 64 + (((d >> 3) ^ ((ka  >> 3) & 7)) * 8) + (d & 7)];
        unsigned int hi = t[kb2 * 64 + (((d >> 3) ^ ((kb2 >> 3) & 7)) * 8) + (d & 7)];
        wd[jj] = lo | (hi << 16);
      }
      int4 o; o.x = wd[0]; o.y = wd[1]; o.z = wd[2]; o.w = wd[3];
      *(int4*)(Vtp + (size_t)d * KLEN + kv0 + k8 * 8) = o;
    }
  }
}

// ---------------- flash attention (KVB=128, reg-staged pipeline, V pre-transposed) ----
// grid (33 qblocks, 8 heads, 4 batch); 4 waves, wave w owns q rows q0+w*16..+15
// NOTE: plain __launch_bounds__(256) — R2's (256,3) forced VGPR<=85 -> spills (perf loss
// + graph-scratch risk). LDS 52KB still allows 3 blocks/CU.
__global__ __launch_bounds__(256) void attn_kernel(const unsigned short* __restrict__ Qb,
                                                   const unsigned short* __restrict__ Kb,
                                                   const unsigned short* __restrict__ Vtg,
                                                   unsigned short* __restrict__ Att) {
  __shared__ unsigned short Ks[KVB * KP];     // 18432 B  [kv][d]
  __shared__ unsigned short Vs[HDIM * VP];    // 17408 B  [d][kv]
  __shared__ unsigned short Ps[4][16 * PP];   // 17408 B  per-wave [q][kv]

  const int tid = threadIdx.x;
  const int w = tid >> 6, l = tid & 63;
  const int lg = l >> 4, lr = l & 15;
  const int qb = 32 - (int)blockIdx.x;                 // big blocks first
  const int bh = (int)blockIdx.z * NHEAD + (int)blockIdx.y;
  const int q0 = qb * 64;
  const int base = NXT + q0;
  const int nkb = (base + 64 + 127) >> 7;

  const unsigned short* Qh = Qb + (size_t)bh * QLEN * HDIM;
  const unsigned short* Kh = Kb + (size_t)bh * KLEN * HDIM;
  const unsigned short* Vh = Vtg + (size_t)bh * HDIM * KLEN;   // [64][KLEN]

  int qrow = q0 + w * 16 + lr; if (qrow > QLEN - 1) qrow = QLEN - 1;
  const bf16x8 qa0 = *(const bf16x8*)(Qh + (size_t)qrow * HDIM + lg * 8);
  const bf16x8 qa1 = *(const bf16x8*)(Qh + (size_t)qrow * HDIM + 32 + lg * 8);

  f32x4 acc[4];
#pragma unroll
  for (int n = 0; n < 4; ++n) acc[n] = (f32x4){0.f, 0.f, 0.f, 0.f};
  float m_r[4], lsum[4];
#pragma unroll
  for (int r = 0; r < 4; ++r) { m_r[r] = -1e30f; lsum[r] = 0.f; }

  const int krow = tid >> 3, kcol = (tid & 7) * 8;     // K stage coords (+i*32 rows)
  const int vrow = tid >> 4, vcol = (tid & 15) * 8;    // V stage coords (+i*16 rows)

  int4 gk[4], gv[4];
#pragma unroll
  for (int i = 0; i < 4; ++i) {                        // prefetch tile 0
    gk[i] = *(const int4*)(Kh + (size_t)(i * 32 + krow) * HDIM + kcol);
    gv[i] = *(const int4*)(Vh + (size_t)(i * 16 + vrow) * KLEN + vcol);
  }

  for (int kb = 0; kb < nkb; ++kb) {
    const int kv0 = kb * KVB;
    if (kb) __syncthreads();                           // prior tile's readers done
#pragma unroll
    for (int i = 0; i < 4; ++i) {                      // regs -> LDS (b128, conflict-free)
      *(int4*)&Ks[(i * 32 + krow) * KP + kcol] = gk[i];
      *(int4*)&Vs[(i * 16 + vrow) * VP + vcol] = gv[i];
    }
    __syncthreads();                                   // tile ready
    if (kb + 1 < nkb) {                                // T14: issue next tile during compute
      const int nv0 = kv0 + KVB;
#pragma unroll
      for (int i = 0; i < 4; ++i) {
        int rr = nv0 + i * 32 + krow; if (rr > KLEN - 1) rr = KLEN - 1;
        gk[i] = *(const int4*)(Kh + (size_t)rr * HDIM + kcol);
        int cc = nv0 + vcol; if (cc > KLEN - 8) cc = KLEN - 8;
        gv[i] = *(const int4*)(Vh + (size_t)(i * 16 + vrow) * KLEN + cc);
      }
    }

    // S = Q K^T : 16 q-rows x 128 keys per wave
    f32x4 s[8];
#pragma unroll
    for (int n = 0; n < 8; ++n) {
      const bf16x8 k0 = *(const bf16x8*)&Ks[(n * 16 + lr) * KP + lg * 8];
      const bf16x8 k1 = *(const bf16x8*)&Ks[(n * 16 + lr) * KP + 32 + lg * 8];
      s[n] = mfma16(qa0, k0, (f32x4){0.f, 0.f, 0.f, 0.f});
      s[n] = mfma16(qa1, k1, s[n]);
    }

    if (kb == nkb - 1) {                               // causal mask, last tile only
#pragma unroll
      for (int n = 0; n < 8; ++n) {
        const int kc = kv0 + n * 16 + lr;
#pragma unroll
        for (int r = 0; r < 4; ++r)
          if (kc > base + w * 16 + lg * 4 + r) s[n][r] = -1e30f;
      }
    }

    // online softmax: row r lives on 16-lane group
    float rmax[4];
#pragma unroll
    for (int r = 0; r < 4; ++r) {
      float v = s[0][r];
#pragma unroll
      for (int n = 1; n < 8; ++n) v = fmaxf(v, s[n][r]);
      v = fmaxf(v, __shfl_xor(v, 1)); v = fmaxf(v, __shfl_xor(v, 2));
      v = fmaxf(v, __shfl_xor(v, 4)); v = fmaxf(v, __shfl_xor(v, 8));
      rmax[r] = v;
    }
    int grow = (rmax[0] > m_r[0] + 8.f) | (rmax[1] > m_r[1] + 8.f) |
               (rmax[2] > m_r[2] + 8.f) | (rmax[3] > m_r[3] + 8.f);
    if (__any(grow)) {                                 // T13 defer-max
#pragma unroll
      for (int r = 0; r < 4; ++r) {
        float mn = fmaxf(m_r[r], rmax[r]);
        float sc = __expf(m_r[r] - mn);
        lsum[r] *= sc;
#pragma unroll
        for (int n = 0; n < 4; ++n) acc[n][r] *= sc;
        m_r[r] = mn;
      }
    }
    float rsum[4] = {0.f, 0.f, 0.f, 0.f};
#pragma unroll
    for (int n = 0; n < 8; ++n)
#pragma unroll
      for (int r = 0; r < 4; ++r) {
        float p = __expf(s[n][r] - m_r[r]);
        s[n][r] = p; rsum[r] += p;
      }
#pragma unroll
    for (int r = 0; r < 4; ++r) {
      float v = rsum[r];
      v += __shfl_xor(v, 1); v += __shfl_xor(v, 2);
      v += __shfl_xor(v, 4); v += __shfl_xor(v, 8);
      lsum[r] += v;
    }

    // P -> LDS (per-wave), round-half-up to bf16
    unsigned short* Pw = &Ps[w][0];
#pragma unroll
    for (int n = 0; n < 8; ++n)
#pragma unroll
      for (int r = 0; r < 4; ++r) {
        unsigned int u = __float_as_uint(s[n][r]) + 0x8000u;
        Pw[(lg * 4 + r) * PP + n * 16 + lr] = (unsigned short)(u >> 16);
      }
    asm volatile("s_waitcnt lgkmcnt(0)" ::: "memory");
    __builtin_amdgcn_sched_barrier(0);                 // rule #18: pin MFMA below the wait
    bf16x8 pa[4];
#pragma unroll
    for (int ks = 0; ks < 4; ++ks) pa[ks] = *(const bf16x8*)&Pw[lr * PP + ks * 32 + lg * 8];
#pragma unroll
    for (int n = 0; n < 4; ++n)
#pragma unroll
      for (int ks = 0; ks < 4; ++ks) {
        const bf16x8 vv = *(const bf16x8*)&Vs[(n * 16 + lr) * VP + ks * 32 + lg * 8];
        acc[n] = mfma16(pa[ks], vv, acc[n]);
      }
  }

  float inv[4];
#pragma unroll
  for (int r = 0; r < 4; ++r) inv[r] = 1.f / lsum[r];
#pragma unroll
  for (int n = 0; n < 4; ++n)
#pragma unroll
    for (int r = 0; r < 4; ++r) {
      int qi = q0 + w * 16 + lg * 4 + r;
      if (qi < QLEN)
        Att[((size_t)blockIdx.z * QLEN + qi) * DMODEL + blockIdx.y * HDIM + n * 16 + lr] =
            f2bf(acc[n][r] * inv[r]);
    }
}

// ---------------- output GEMM (unchanged) ----------------
__global__ __launch_bounds__(256) void out_gemm(const unsigned short* __restrict__ A,
                                                const unsigned short* __restrict__ W,
                                                float* __restrict__ Out) {
  __shared__ unsigned short As[128 * 32];
  __shared__ unsigned short Bs[128 * 32];
  const int tid = threadIdx.x;
  const int w = tid >> 6, l = tid & 63;
  const int lg = l >> 4, lr = l & 15;
  const int row0 = blockIdx.x * 128, col0 = blockIdx.y * 128;
  const int wr = (w >> 1) * 64, wc = (w & 1) * 64;

  f32x4 acc[4][4];
#pragma unroll
  for (int m = 0; m < 4; ++m)
#pragma unroll
    for (int n = 0; n < 4; ++n) acc[m][n] = (f32x4){0.f, 0.f, 0.f, 0.f};

  const int sr = w * 16 + (l >> 2);
  const int sc = (l & 3) * 8;

  for (int k0 = 0; k0 < 512; k0 += 32) {
#pragma unroll
    for (int i = 0; i < 2; ++i) {
      const unsigned short* gpa = A + (size_t)(row0 + sr + i * 64) * 512 + k0 + sc;
      gload_lds16(gpa, (char*)As + i * 4096 + w * 1024);
      const unsigned short* gpb = W + (size_t)(col0 + sr + i * 64) * 512 + k0 + sc;
      gload_lds16(gpb, (char*)Bs + i * 4096 + w * 1024);
    }
    __syncthreads();
    bf16x8 av[4], bv[4];
#pragma unroll
    for (int m = 0; m < 4; ++m) av[m] = *(const bf16x8*)&As[(wr + m * 16 + lr) * 32 + lg * 8];
#pragma unroll
    for (int n = 0; n < 4; ++n) bv[n] = *(const bf16x8*)&Bs[(wc + n * 16 + lr) * 32 + lg * 8];
#pragma unroll
    for (int m = 0; m < 4; ++m)
#pragma unroll
      for (int n = 0; n < 4; ++n) acc[m][n] = mfma16(av[m], bv[n], acc[m][n]);
    __syncthreads();
  }

#pragma unroll
  for (int m = 0; m < 4; ++m) {
    int crow = row0 + wr + m * 16 + lg * 4;
#pragma unroll
    for (int n = 0; n < 4; ++n) {
      int ccol = col0 + wc + n * 16 + lr;
#pragma unroll
      for (int r = 0; r < 4; ++r) {
        int cr = crow + r;
        int bb = cr / QLEN, ii = cr - bb * QLEN;
        size_t off = ii < NXT
                       ? ((size_t)bb * NXT + ii) * DMODEL + ccol
                       : (size_t)NBATCH * NXT * DMODEL + ((size_t)bb * NSN + (ii - NXT)) * DMODEL + ccol;
        Out[off] = acc[m][n][r];
      }
    }
  }
}

// ---------------- host launch ----------------
extern "C" void kernel_launch(void* const* d_in, const int* in_sizes, int n_in,
                              void* d_out, int out_size, void* d_ws, size_t ws_size,
                              hipStream_t stream) {
  const float* seq = (const float*)d_in[0];
  const float* nst = (const float*)d_in[2];
  const float* Wq  = (const float*)d_in[5];
  const float* Wk  = (const float*)d_in[6];
  const float* Wv  = (const float*)d_in[7];
  const float* nsq = (const float*)d_in[8];
  const float* nsk = (const float*)d_in[9];
  const float* nsv = (const float*)d_in[10];
  const float* Wo  = (const float*)d_in[11];
  float* out = (float*)d_out;

  // fully disjoint workspace layout (no aliasing)
  char* ws = (char*)d_ws;
  unsigned short* Xbf  = (unsigned short*)(ws);                       // 16,777,216
  unsigned short* Wqb  = (unsigned short*)(ws + 16777216);            // 524,288 x4
  unsigned short* Wkb  = Wqb + 262144;
  unsigned short* Wvb  = Wkb + 262144;
  unsigned short* Wob  = Wvb + 262144;
  unsigned short* Qbuf = (unsigned short*)(ws + 18874368);            // 8,519,680
  unsigned short* Kbuf = (unsigned short*)(ws + 27394048);            // 16,908,288
  unsigned short* Vbuf = (unsigned short*)(ws + 44302336);            // 16,908,288
  unsigned short* Att  = (unsigned short*)(ws + 61210624);            // 8,519,680
  unsigned short* Vtg  = (unsigned short*)(ws + 69730304);            // 16,908,288 -> total 86,638,592
  if (ws_size < 86638592) return;   // insufficient scratch -> visible first-call failure

  cvt_f32_bf16_v4<<<dim3(8192), dim3(256), 0, stream>>>(seq, Xbf, 2097152);
  cvt_w4<<<dim3(256, 4), dim3(256), 0, stream>>>(Wq, Wk, Wv, Wo, Wqb);
  proj_gemm<<<dim3(128, 4), dim3(256), 0, stream>>>(Xbf, Wkb, Kbuf, 12, 0, KLEN, 1.f);
  proj_gemm<<<dim3(128, 4), dim3(256), 0, stream>>>(Xbf, Wvb, Vbuf, 12, 0, KLEN, 1.f);
  proj_gemm<<<dim3(64, 4), dim3(256), 0, stream>>>(Xbf, Wqb, Qbuf, 11, 2048, QLEN, 0.125f);
  ns_proj<<<dim3(4, 32, 3), dim3(256), 0, stream>>>(nst, nsq, nsk, nsv, Qbuf, Kbuf, Vbuf);
  vtrans<<<dim3(65, 32), dim3(256), 0, stream>>>(Vbuf, Vtg);
  attn_kernel<<<dim3(33, 8, 4), dim3(256), 0, stream>>>(Qbuf, Kbuf, Vtg, Att);
  out_gemm<<<dim3(65, 4), dim3(256), 0, stream>>>(Att, Wob, out);
}

// Round 4
// 438.016 us; speedup vs baseline: 1.0119x; 1.0049x over previous
//
#include <hip/hip_runtime.h>

// ---------------- problem constants ----------------
#define NBATCH 4
#define SEQ    4096
#define DMODEL 512
#define NHEAD  8
#define HDIM   64
#define NSN    32
#define NXT    2048
#define QLEN   2080   // NXT + NSN
#define KLEN   4128   // SEQ + NSN

// attention tile geometry
#define KVB 128       // keys per LDS tile
#define KP  72        // Ks row stride (elems): 144B, 16B-aligned
#define VP  136       // Vs row stride
#define PP  136       // Ps row stride

using bf16x8 = __attribute__((ext_vector_type(8))) short;
using f32x4  = __attribute__((ext_vector_type(4))) float;

typedef __attribute__((address_space(1))) unsigned int gu32;
typedef __attribute__((address_space(3))) unsigned int lu32;

__device__ __forceinline__ unsigned short f2bf(float f) {
  unsigned int u = __float_as_uint(f);
  u += 0x7FFF + ((u >> 16) & 1);          // RTNE
  return (unsigned short)(u >> 16);
}

__device__ __forceinline__ f32x4 mfma16(bf16x8 a, bf16x8 b, f32x4 c) {
  return __builtin_amdgcn_mfma_f32_16x16x32_bf16(a, b, c, 0, 0, 0);
}

__device__ __forceinline__ void gload_lds16(const void* g, void* lds_base) {
  __builtin_amdgcn_global_load_lds((const gu32*)g, (lu32*)lds_base, 16, 0, 0);
}

// ---------------- fp32 -> bf16 converts ----------------
__global__ __launch_bounds__(256) void cvt_f32_bf16_v4(const float* __restrict__ src,
                                                       unsigned short* __restrict__ dst, int n4) {
  int i = blockIdx.x * 256 + threadIdx.x;
  if (i >= n4) return;
  float4 v = reinterpret_cast<const float4*>(src)[i];
  ushort4 r;
  r.x = f2bf(v.x); r.y = f2bf(v.y); r.z = f2bf(v.z); r.w = f2bf(v.w);
  reinterpret_cast<ushort4*>(dst)[i] = r;
}

__global__ __launch_bounds__(256) void cvt_w4(const float* __restrict__ a, const float* __restrict__ b,
                                              const float* __restrict__ c, const float* __restrict__ d,
                                              unsigned short* __restrict__ dst) {
  const float* s = blockIdx.y == 0 ? a : blockIdx.y == 1 ? b : blockIdx.y == 2 ? c : d;
  int i = blockIdx.x * 256 + threadIdx.x;   // 65536 float4 per matrix
  float4 v = reinterpret_cast<const float4*>(s)[i];
  ushort4 r;
  r.x = f2bf(v.x); r.y = f2bf(v.y); r.z = f2bf(v.z); r.w = f2bf(v.w);
  reinterpret_cast<ushort4*>(dst)[(size_t)blockIdx.y * 65536 + i] = r;
}

// ---------------- seq projection GEMM (m97 structure, known-good) ----------------
__global__ __launch_bounds__(256) void proj_gemm(const unsigned short* __restrict__ X,
                                                 const unsigned short* __restrict__ W,
                                                 unsigned short* __restrict__ Out,
                                                 int rpb_shift, int row_off, int out_L, float scale) {
  __shared__ unsigned short As[128 * 32];
  __shared__ unsigned short Bs[128 * 32];
  const int tid = threadIdx.x;
  const int w = tid >> 6, l = tid & 63;
  const int lg = l >> 4, lr = l & 15;
  const int row0 = blockIdx.x * 128, col0 = blockIdx.y * 128;
  const int wr = (w >> 1) * 64, wc = (w & 1) * 64;
  const int mask = (1 << rpb_shift) - 1;

  f32x4 acc[4][4];
#pragma unroll
  for (int m = 0; m < 4; ++m)
#pragma unroll
    for (int n = 0; n < 4; ++n) acc[m][n] = (f32x4){0.f, 0.f, 0.f, 0.f};

  const int sr = w * 16 + (l >> 2);
  const int sc = (l & 3) * 8;

  for (int k0 = 0; k0 < 512; k0 += 32) {
#pragma unroll
    for (int i = 0; i < 2; ++i) {
      int gr = row0 + sr + i * 64;
      int xrow = ((gr >> rpb_shift) << 12) + row_off + (gr & mask);
      const unsigned short* gpa = X + (size_t)xrow * 512 + k0 + sc;
      gload_lds16(gpa, (char*)As + i * 4096 + w * 1024);
      const unsigned short* gpb = W + (size_t)(col0 + sr + i * 64) * 512 + k0 + sc;
      gload_lds16(gpb, (char*)Bs + i * 4096 + w * 1024);
    }
    __syncthreads();
    bf16x8 av[4], bv[4];
#pragma unroll
    for (int m = 0; m < 4; ++m) av[m] = *(const bf16x8*)&As[(wr + m * 16 + lr) * 32 + lg * 8];
#pragma unroll
    for (int n = 0; n < 4; ++n) bv[n] = *(const bf16x8*)&Bs[(wc + n * 16 + lr) * 32 + lg * 8];
#pragma unroll
    for (int m = 0; m < 4; ++m)
#pragma unroll
      for (int n = 0; n < 4; ++n) acc[m][n] = mfma16(av[m], bv[n], acc[m][n]);
    __syncthreads();
  }

#pragma unroll
  for (int m = 0; m < 4; ++m) {
    int crow = row0 + wr + m * 16 + lg * 4;
#pragma unroll
    for (int n = 0; n < 4; ++n) {
      int ccol = col0 + wc + n * 16 + lr;
      int hh = ccol >> 6, dd = ccol & 63;
#pragma unroll
      for (int r = 0; r < 4; ++r) {
        int cr = crow + r;
        int bb = cr >> rpb_shift, ii = cr & mask;
        Out[(((size_t)bb * NHEAD + hh) * out_L + ii) * HDIM + dd] = f2bf(acc[m][n][r] * scale);
      }
    }
  }
}

// ---------------- ns projections (unchanged) ----------------
__global__ __launch_bounds__(256) void ns_proj(const float* __restrict__ nst,
                                               const float* __restrict__ Wnq, const float* __restrict__ Wnk,
                                               const float* __restrict__ Wnv,
                                               unsigned short* __restrict__ Qb, unsigned short* __restrict__ Kb,
                                               unsigned short* __restrict__ Vb) {
  const int oc = blockIdx.x, n = blockIdx.y, p = blockIdx.z;
  const float* W = p == 0 ? Wnq : p == 1 ? Wnk : Wnv;
  unsigned short* Out = p == 0 ? Qb : p == 1 ? Kb : Vb;
  const int out_L = p == 0 ? QLEN : KLEN;
  const int orow = p == 0 ? NXT + n : SEQ + n;
  const float scale = p == 0 ? 0.125f : 1.f;

  __shared__ float xs[NBATCH][DMODEL];
  __shared__ float red[NBATCH][128];
  const int tid = threadIdx.x;
  for (int idx = tid; idx < NBATCH * DMODEL; idx += 256)
    xs[idx >> 9][idx & 511] = nst[(size_t)((idx >> 9) * NSN + n) * DMODEL + (idx & 511)];
  __syncthreads();

  const int o = oc * 128 + (tid & 127);
  const int dh = tid >> 7;
  float a0 = 0.f, a1 = 0.f, a2 = 0.f, a3 = 0.f;
  const float* wp = W + (size_t)n * DMODEL * DMODEL + o;
#pragma unroll 8
  for (int d = dh * 256; d < dh * 256 + 256; ++d) {
    float wv = wp[(size_t)d * DMODEL];
    a0 += xs[0][d] * wv; a1 += xs[1][d] * wv; a2 += xs[2][d] * wv; a3 += xs[3][d] * wv;
  }
  if (dh == 1) { red[0][tid & 127] = a0; red[1][tid & 127] = a1; red[2][tid & 127] = a2; red[3][tid & 127] = a3; }
  __syncthreads();
  if (dh == 0) {
    a0 += red[0][tid & 127]; a1 += red[1][tid & 127]; a2 += red[2][tid & 127]; a3 += red[3][tid & 127];
    int hh = o >> 6, dd = o & 63;
    float v[4] = {a0, a1, a2, a3};
#pragma unroll
    for (int b = 0; b < NBATCH; ++b)
      Out[(((size_t)b * NHEAD + hh) * out_L + orow) * HDIM + dd] = f2bf(v[b] * scale);
  }
}

// ---------------- global V transpose: Vt[bh][d][kv] = V[bh][kv][d] ----------------
__global__ __launch_bounds__(256) void vtrans(const unsigned short* __restrict__ V,
                                              unsigned short* __restrict__ Vt) {
  __shared__ unsigned short t[64 * 64];
  const int tid = threadIdx.x;
  const int kv0 = blockIdx.x * 64, bh = blockIdx.y;
  const unsigned short* Vhp = V + (size_t)bh * KLEN * HDIM;
  unsigned short* Vtp = Vt + (size_t)bh * HDIM * KLEN;

#pragma unroll
  for (int i = 0; i < 2; ++i) {
    int c = i * 256 + tid;             // 512 chunks of 16B: row = kv-local, c8 = d-chunk
    int row = c >> 3, c8 = c & 7;
    int kvg = kv0 + row; if (kvg > KLEN - 1) kvg = KLEN - 1;
    int4 v4 = *(const int4*)(Vhp + (size_t)kvg * HDIM + c8 * 8);
    *(int4*)&t[row * 64 + ((c8 ^ ((row >> 3) & 7)) * 8)] = v4;
  }
  __syncthreads();
#pragma unroll
  for (int i = 0; i < 2; ++i) {
    int c = i * 256 + tid;             // 512: d row, k8 = kv-chunk
    int d = c >> 3, k8 = c & 7;
    if (kv0 + k8 * 8 <= KLEN - 8) {
      unsigned int wd[4];
#pragma unroll
      for (int jj = 0; jj < 4; ++jj) {
        int ka = k8 * 8 + jj * 2, kb2 = ka + 1;
        unsigned int lo = t[ka  * 64 + (((d >> 3) ^ ((ka  >> 3) & 7)) * 8) + (d & 7)];
        unsigned int hi = t[kb2 * 64 + (((d >> 3) ^ ((kb2 >> 3) & 7)) * 8) + (d & 7)];
        wd[jj] = lo | (hi << 16);
      }
      int4 o; o.x = wd[0]; o.y = wd[1]; o.z = wd[2]; o.w = wd[3];
      *(int4*)(Vtp + (size_t)d * KLEN + kv0 + k8 * 8) = o;
    }
  }
}

// ---------------- flash attention (KVB=128, reg-staged pipeline, V pre-transposed) ----
// grid (33 qblocks, 8 heads, 4 batch); 4 waves, wave w owns q rows q0+w*16..+15
// __launch_bounds__(256, 2): min 2 waves/EU -> VGPR budget 256. R3's bare (256) let the
// backend pick ~7 waves/EU -> 72 VGPRs -> per-tile spill of the ~130-reg working set
// (counters: WRITE_SIZE 735 MB vs 8.5 MB of real output; 1.05 GB HBM/dispatch).
// Real occupancy stays LDS-bound: 52 KB -> 3 blocks/CU = 3 waves/EU.
__global__ __launch_bounds__(256, 2) void attn_kernel(const unsigned short* __restrict__ Qb,
                                                      const unsigned short* __restrict__ Kb,
                                                      const unsigned short* __restrict__ Vtg,
                                                      unsigned short* __restrict__ Att) {
  __shared__ unsigned short Ks[KVB * KP];     // 18432 B  [kv][d]
  __shared__ unsigned short Vs[HDIM * VP];    // 17408 B  [d][kv]
  __shared__ unsigned short Ps[4][16 * PP];   // 17408 B  per-wave [q][kv]

  const int tid = threadIdx.x;
  const int w = tid >> 6, l = tid & 63;
  const int lg = l >> 4, lr = l & 15;
  const int qb = 32 - (int)blockIdx.x;                 // big blocks first
  const int bh = (int)blockIdx.z * NHEAD + (int)blockIdx.y;
  const int q0 = qb * 64;
  const int base = NXT + q0;
  const int nkb = (base + 64 + 127) >> 7;

  const unsigned short* Qh = Qb + (size_t)bh * QLEN * HDIM;
  const unsigned short* Kh = Kb + (size_t)bh * KLEN * HDIM;
  const unsigned short* Vh = Vtg + (size_t)bh * HDIM * KLEN;   // [64][KLEN]

  int qrow = q0 + w * 16 + lr; if (qrow > QLEN - 1) qrow = QLEN - 1;
  const bf16x8 qa0 = *(const bf16x8*)(Qh + (size_t)qrow * HDIM + lg * 8);
  const bf16x8 qa1 = *(const bf16x8*)(Qh + (size_t)qrow * HDIM + 32 + lg * 8);

  f32x4 acc[4];
#pragma unroll
  for (int n = 0; n < 4; ++n) acc[n] = (f32x4){0.f, 0.f, 0.f, 0.f};
  float m_r[4], lsum[4];
#pragma unroll
  for (int r = 0; r < 4; ++r) { m_r[r] = -1e30f; lsum[r] = 0.f; }

  const int krow = tid >> 3, kcol = (tid & 7) * 8;     // K stage coords (+i*32 rows)
  const int vrow = tid >> 4, vcol = (tid & 15) * 8;    // V stage coords (+i*16 rows)

  int4 gk[4], gv[4];
#pragma unroll
  for (int i = 0; i < 4; ++i) {                        // prefetch tile 0
    gk[i] = *(const int4*)(Kh + (size_t)(i * 32 + krow) * HDIM + kcol);
    gv[i] = *(const int4*)(Vh + (size_t)(i * 16 + vrow) * KLEN + vcol);
  }

  for (int kb = 0; kb < nkb; ++kb) {
    const int kv0 = kb * KVB;
    if (kb) __syncthreads();                           // prior tile's readers done
#pragma unroll
    for (int i = 0; i < 4; ++i) {                      // regs -> LDS (b128, conflict-free)
      *(int4*)&Ks[(i * 32 + krow) * KP + kcol] = gk[i];
      *(int4*)&Vs[(i * 16 + vrow) * VP + vcol] = gv[i];
    }
    __syncthreads();                                   // tile ready
    if (kb + 1 < nkb) {                                // T14: issue next tile during compute
      const int nv0 = kv0 + KVB;
#pragma unroll
      for (int i = 0; i < 4; ++i) {
        int rr = nv0 + i * 32 + krow; if (rr > KLEN - 1) rr = KLEN - 1;
        gk[i] = *(const int4*)(Kh + (size_t)rr * HDIM + kcol);
        int cc = nv0 + vcol; if (cc > KLEN - 8) cc = KLEN - 8;
        gv[i] = *(const int4*)(Vh + (size_t)(i * 16 + vrow) * KLEN + cc);
      }
    }

    // S = Q K^T : 16 q-rows x 128 keys per wave
    f32x4 s[8];
#pragma unroll
    for (int n = 0; n < 8; ++n) {
      const bf16x8 k0 = *(const bf16x8*)&Ks[(n * 16 + lr) * KP + lg * 8];
      const bf16x8 k1 = *(const bf16x8*)&Ks[(n * 16 + lr) * KP + 32 + lg * 8];
      s[n] = mfma16(qa0, k0, (f32x4){0.f, 0.f, 0.f, 0.f});
      s[n] = mfma16(qa1, k1, s[n]);
    }

    if (kb == nkb - 1) {                               // causal mask, last tile only
#pragma unroll
      for (int n = 0; n < 8; ++n) {
        const int kc = kv0 + n * 16 + lr;
#pragma unroll
        for (int r = 0; r < 4; ++r)
          if (kc > base + w * 16 + lg * 4 + r) s[n][r] = -1e30f;
      }
    }

    // online softmax: row r lives on 16-lane group
    float rmax[4];
#pragma unroll
    for (int r = 0; r < 4; ++r) {
      float v = s[0][r];
#pragma unroll
      for (int n = 1; n < 8; ++n) v = fmaxf(v, s[n][r]);
      v = fmaxf(v, __shfl_xor(v, 1)); v = fmaxf(v, __shfl_xor(v, 2));
      v = fmaxf(v, __shfl_xor(v, 4)); v = fmaxf(v, __shfl_xor(v, 8));
      rmax[r] = v;
    }
    int grow = (rmax[0] > m_r[0] + 8.f) | (rmax[1] > m_r[1] + 8.f) |
               (rmax[2] > m_r[2] + 8.f) | (rmax[3] > m_r[3] + 8.f);
    if (__any(grow)) {                                 // T13 defer-max
#pragma unroll
      for (int r = 0; r < 4; ++r) {
        float mn = fmaxf(m_r[r], rmax[r]);
        float sc = __expf(m_r[r] - mn);
        lsum[r] *= sc;
#pragma unroll
        for (int n = 0; n < 4; ++n) acc[n][r] *= sc;
        m_r[r] = mn;
      }
    }
    float rsum[4] = {0.f, 0.f, 0.f, 0.f};
#pragma unroll
    for (int n = 0; n < 8; ++n)
#pragma unroll
      for (int r = 0; r < 4; ++r) {
        float p = __expf(s[n][r] - m_r[r]);
        s[n][r] = p; rsum[r] += p;
      }
#pragma unroll
    for (int r = 0; r < 4; ++r) {
      float v = rsum[r];
      v += __shfl_xor(v, 1); v += __shfl_xor(v, 2);
      v += __shfl_xor(v, 4); v += __shfl_xor(v, 8);
      lsum[r] += v;
    }

    // P -> LDS (per-wave), round-half-up to bf16
    unsigned short* Pw = &Ps[w][0];
#pragma unroll
    for (int n = 0; n < 8; ++n)
#pragma unroll
      for (int r = 0; r < 4; ++r) {
        unsigned int u = __float_as_uint(s[n][r]) + 0x8000u;
        Pw[(lg * 4 + r) * PP + n * 16 + lr] = (unsigned short)(u >> 16);
      }
    asm volatile("s_waitcnt lgkmcnt(0)" ::: "memory");
    __builtin_amdgcn_sched_barrier(0);                 // rule #18: pin MFMA below the wait
    bf16x8 pa[4];
#pragma unroll
    for (int ks = 0; ks < 4; ++ks) pa[ks] = *(const bf16x8*)&Pw[lr * PP + ks * 32 + lg * 8];
#pragma unroll
    for (int n = 0; n < 4; ++n)
#pragma unroll
      for (int ks = 0; ks < 4; ++ks) {
        const bf16x8 vv = *(const bf16x8*)&Vs[(n * 16 + lr) * VP + ks * 32 + lg * 8];
        acc[n] = mfma16(pa[ks], vv, acc[n]);
      }
  }

  float inv[4];
#pragma unroll
  for (int r = 0; r < 4; ++r) inv[r] = 1.f / lsum[r];
#pragma unroll
  for (int n = 0; n < 4; ++n)
#pragma unroll
    for (int r = 0; r < 4; ++r) {
      int qi = q0 + w * 16 + lg * 4 + r;
      if (qi < QLEN)
        Att[((size_t)blockIdx.z * QLEN + qi) * DMODEL + blockIdx.y * HDIM + n * 16 + lr] =
            f2bf(acc[n][r] * inv[r]);
    }
}

// ---------------- output GEMM (unchanged) ----------------
__global__ __launch_bounds__(256) void out_gemm(const unsigned short* __restrict__ A,
                                                const unsigned short* __restrict__ W,
                                                float* __restrict__ Out) {
  __shared__ unsigned short As[128 * 32];
  __shared__ unsigned short Bs[128 * 32];
  const int tid = threadIdx.x;
  const int w = tid >> 6, l = tid & 63;
  const int lg = l >> 4, lr = l & 15;
  const int row0 = blockIdx.x * 128, col0 = blockIdx.y * 128;
  const int wr = (w >> 1) * 64, wc = (w & 1) * 64;

  f32x4 acc[4][4];
#pragma unroll
  for (int m = 0; m < 4; ++m)
#pragma unroll
    for (int n = 0; n < 4; ++n) acc[m][n] = (f32x4){0.f, 0.f, 0.f, 0.f};

  const int sr = w * 16 + (l >> 2);
  const int sc = (l & 3) * 8;

  for (int k0 = 0; k0 < 512; k0 += 32) {
#pragma unroll
    for (int i = 0; i < 2; ++i) {
      const unsigned short* gpa = A + (size_t)(row0 + sr + i * 64) * 512 + k0 + sc;
      gload_lds16(gpa, (char*)As + i * 4096 + w * 1024);
      const unsigned short* gpb = W + (size_t)(col0 + sr + i * 64) * 512 + k0 + sc;
      gload_lds16(gpb, (char*)Bs + i * 4096 + w * 1024);
    }
    __syncthreads();
    bf16x8 av[4], bv[4];
#pragma unroll
    for (int m = 0; m < 4; ++m) av[m] = *(const bf16x8*)&As[(wr + m * 16 + lr) * 32 + lg * 8];
#pragma unroll
    for (int n = 0; n < 4; ++n) bv[n] = *(const bf16x8*)&Bs[(wc + n * 16 + lr) * 32 + lg * 8];
#pragma unroll
    for (int m = 0; m < 4; ++m)
#pragma unroll
      for (int n = 0; n < 4; ++n) acc[m][n] = mfma16(av[m], bv[n], acc[m][n]);
    __syncthreads();
  }

#pragma unroll
  for (int m = 0; m < 4; ++m) {
    int crow = row0 + wr + m * 16 + lg * 4;
#pragma unroll
    for (int n = 0; n < 4; ++n) {
      int ccol = col0 + wc + n * 16 + lr;
#pragma unroll
      for (int r = 0; r < 4; ++r) {
        int cr = crow + r;
        int bb = cr / QLEN, ii = cr - bb * QLEN;
        size_t off = ii < NXT
                       ? ((size_t)bb * NXT + ii) * DMODEL + ccol
                       : (size_t)NBATCH * NXT * DMODEL + ((size_t)bb * NSN + (ii - NXT)) * DMODEL + ccol;
        Out[off] = acc[m][n][r];
      }
    }
  }
}

// ---------------- host launch ----------------
extern "C" void kernel_launch(void* const* d_in, const int* in_sizes, int n_in,
                              void* d_out, int out_size, void* d_ws, size_t ws_size,
                              hipStream_t stream) {
  const float* seq = (const float*)d_in[0];
  const float* nst = (const float*)d_in[2];
  const float* Wq  = (const float*)d_in[5];
  const float* Wk  = (const float*)d_in[6];
  const float* Wv  = (const float*)d_in[7];
  const float* nsq = (const float*)d_in[8];
  const float* nsk = (const float*)d_in[9];
  const float* nsv = (const float*)d_in[10];
  const float* Wo  = (const float*)d_in[11];
  float* out = (float*)d_out;

  // fully disjoint workspace layout (no aliasing)
  char* ws = (char*)d_ws;
  unsigned short* Xbf  = (unsigned short*)(ws);                       // 16,777,216
  unsigned short* Wqb  = (unsigned short*)(ws + 16777216);            // 524,288 x4
  unsigned short* Wkb  = Wqb + 262144;
  unsigned short* Wvb  = Wkb + 262144;
  unsigned short* Wob  = Wvb + 262144;
  unsigned short* Qbuf = (unsigned short*)(ws + 18874368);            // 8,519,680
  unsigned short* Kbuf = (unsigned short*)(ws + 27394048);            // 16,908,288
  unsigned short* Vbuf = (unsigned short*)(ws + 44302336);            // 16,908,288
  unsigned short* Att  = (unsigned short*)(ws + 61210624);            // 8,519,680
  unsigned short* Vtg  = (unsigned short*)(ws + 69730304);            // 16,908,288 -> total 86,638,592
  if (ws_size < 86638592) return;   // insufficient scratch -> visible first-call failure

  cvt_f32_bf16_v4<<<dim3(8192), dim3(256), 0, stream>>>(seq, Xbf, 2097152);
  cvt_w4<<<dim3(256, 4), dim3(256), 0, stream>>>(Wq, Wk, Wv, Wo, Wqb);
  proj_gemm<<<dim3(128, 4), dim3(256), 0, stream>>>(Xbf, Wkb, Kbuf, 12, 0, KLEN, 1.f);
  proj_gemm<<<dim3(128, 4), dim3(256), 0, stream>>>(Xbf, Wvb, Vbuf, 12, 0, KLEN, 1.f);
  proj_gemm<<<dim3(64, 4), dim3(256), 0, stream>>>(Xbf, Wqb, Qbuf, 11, 2048, QLEN, 0.125f);
  ns_proj<<<dim3(4, 32, 3), dim3(256), 0, stream>>>(nst, nsq, nsk, nsv, Qbuf, Kbuf, Vbuf);
  vtrans<<<dim3(65, 32), dim3(256), 0, stream>>>(Vbuf, Vtg);
  attn_kernel<<<dim3(33, 8, 4), dim3(256), 0, stream>>>(Qbuf, Kbuf, Vtg, Att);
  out_gemm<<<dim3(65, 4), dim3(256), 0, stream>>>(Att, Wob, out);
}

// Round 5
// 327.168 us; speedup vs baseline: 1.3547x; 1.3388x over previous
//
#include <hip/hip_runtime.h>

// ---------------- problem constants ----------------
#define NBATCH 4
#define SEQ    4096
#define DMODEL 512
#define NHEAD  8
#define HDIM   64
#define NSN    32
#define NXT    2048
#define QLEN   2080   // NXT + NSN
#define KLEN   4128   // SEQ + NSN

#define PP  72        // Ps row stride (144B = 9*16B aligned)

using bf16x8 = __attribute__((ext_vector_type(8))) short;
using f32x4  = __attribute__((ext_vector_type(4))) float;

typedef __attribute__((address_space(1))) unsigned int gu32;
typedef __attribute__((address_space(3))) unsigned int lu32;

__device__ __forceinline__ unsigned short f2bf(float f) {
  unsigned int u = __float_as_uint(f);
  u += 0x7FFF + ((u >> 16) & 1);          // RTNE
  return (unsigned short)(u >> 16);
}

__device__ __forceinline__ f32x4 mfma16(bf16x8 a, bf16x8 b, f32x4 c) {
  return __builtin_amdgcn_mfma_f32_16x16x32_bf16(a, b, c, 0, 0, 0);
}

__device__ __forceinline__ void gload_lds16(const void* g, void* lds_base) {
  __builtin_amdgcn_global_load_lds((const gu32*)g, (lu32*)lds_base, 16, 0, 0);
}

// ---------------- fp32 -> bf16 converts ----------------
__global__ __launch_bounds__(256) void cvt_f32_bf16_v4(const float* __restrict__ src,
                                                       unsigned short* __restrict__ dst, int n4) {
  int i = blockIdx.x * 256 + threadIdx.x;
  if (i >= n4) return;
  float4 v = reinterpret_cast<const float4*>(src)[i];
  ushort4 r;
  r.x = f2bf(v.x); r.y = f2bf(v.y); r.z = f2bf(v.z); r.w = f2bf(v.w);
  reinterpret_cast<ushort4*>(dst)[i] = r;
}

__global__ __launch_bounds__(256) void cvt_w4(const float* __restrict__ a, const float* __restrict__ b,
                                              const float* __restrict__ c, const float* __restrict__ d,
                                              unsigned short* __restrict__ dst) {
  const float* s = blockIdx.y == 0 ? a : blockIdx.y == 1 ? b : blockIdx.y == 2 ? c : d;
  int i = blockIdx.x * 256 + threadIdx.x;   // 65536 float4 per matrix
  float4 v = reinterpret_cast<const float4*>(s)[i];
  ushort4 r;
  r.x = f2bf(v.x); r.y = f2bf(v.y); r.z = f2bf(v.z); r.w = f2bf(v.w);
  reinterpret_cast<ushort4*>(dst)[(size_t)blockIdx.y * 65536 + i] = r;
}

// ---------------- seq projection GEMM (m97 structure, known-good) ----------------
__global__ __launch_bounds__(256) void proj_gemm(const unsigned short* __restrict__ X,
                                                 const unsigned short* __restrict__ W,
                                                 unsigned short* __restrict__ Out,
                                                 int rpb_shift, int row_off, int out_L, float scale) {
  __shared__ unsigned short As[128 * 32];
  __shared__ unsigned short Bs[128 * 32];
  const int tid = threadIdx.x;
  const int w = tid >> 6, l = tid & 63;
  const int lg = l >> 4, lr = l & 15;
  const int row0 = blockIdx.x * 128, col0 = blockIdx.y * 128;
  const int wr = (w >> 1) * 64, wc = (w & 1) * 64;
  const int mask = (1 << rpb_shift) - 1;

  f32x4 acc[4][4];
#pragma unroll
  for (int m = 0; m < 4; ++m)
#pragma unroll
    for (int n = 0; n < 4; ++n) acc[m][n] = (f32x4){0.f, 0.f, 0.f, 0.f};

  const int sr = w * 16 + (l >> 2);
  const int sc = (l & 3) * 8;

  for (int k0 = 0; k0 < 512; k0 += 32) {
#pragma unroll
    for (int i = 0; i < 2; ++i) {
      int gr = row0 + sr + i * 64;
      int xrow = ((gr >> rpb_shift) << 12) + row_off + (gr & mask);
      const unsigned short* gpa = X + (size_t)xrow * 512 + k0 + sc;
      gload_lds16(gpa, (char*)As + i * 4096 + w * 1024);
      const unsigned short* gpb = W + (size_t)(col0 + sr + i * 64) * 512 + k0 + sc;
      gload_lds16(gpb, (char*)Bs + i * 4096 + w * 1024);
    }
    __syncthreads();
    bf16x8 av[4], bv[4];
#pragma unroll
    for (int m = 0; m < 4; ++m) av[m] = *(const bf16x8*)&As[(wr + m * 16 + lr) * 32 + lg * 8];
#pragma unroll
    for (int n = 0; n < 4; ++n) bv[n] = *(const bf16x8*)&Bs[(wc + n * 16 + lr) * 32 + lg * 8];
#pragma unroll
    for (int m = 0; m < 4; ++m)
#pragma unroll
      for (int n = 0; n < 4; ++n) acc[m][n] = mfma16(av[m], bv[n], acc[m][n]);
    __syncthreads();
  }

#pragma unroll
  for (int m = 0; m < 4; ++m) {
    int crow = row0 + wr + m * 16 + lg * 4;
#pragma unroll
    for (int n = 0; n < 4; ++n) {
      int ccol = col0 + wc + n * 16 + lr;
      int hh = ccol >> 6, dd = ccol & 63;
#pragma unroll
      for (int r = 0; r < 4; ++r) {
        int cr = crow + r;
        int bb = cr >> rpb_shift, ii = cr & mask;
        Out[(((size_t)bb * NHEAD + hh) * out_L + ii) * HDIM + dd] = f2bf(acc[m][n][r] * scale);
      }
    }
  }
}

// ---------------- ns projections (unchanged) ----------------
__global__ __launch_bounds__(256) void ns_proj(const float* __restrict__ nst,
                                               const float* __restrict__ Wnq, const float* __restrict__ Wnk,
                                               const float* __restrict__ Wnv,
                                               unsigned short* __restrict__ Qb, unsigned short* __restrict__ Kb,
                                               unsigned short* __restrict__ Vb) {
  const int oc = blockIdx.x, n = blockIdx.y, p = blockIdx.z;
  const float* W = p == 0 ? Wnq : p == 1 ? Wnk : Wnv;
  unsigned short* Out = p == 0 ? Qb : p == 1 ? Kb : Vb;
  const int out_L = p == 0 ? QLEN : KLEN;
  const int orow = p == 0 ? NXT + n : SEQ + n;
  const float scale = p == 0 ? 0.125f : 1.f;

  __shared__ float xs[NBATCH][DMODEL];
  __shared__ float red[NBATCH][128];
  const int tid = threadIdx.x;
  for (int idx = tid; idx < NBATCH * DMODEL; idx += 256)
    xs[idx >> 9][idx & 511] = nst[(size_t)((idx >> 9) * NSN + n) * DMODEL + (idx & 511)];
  __syncthreads();

  const int o = oc * 128 + (tid & 127);
  const int dh = tid >> 7;
  float a0 = 0.f, a1 = 0.f, a2 = 0.f, a3 = 0.f;
  const float* wp = W + (size_t)n * DMODEL * DMODEL + o;
#pragma unroll 8
  for (int d = dh * 256; d < dh * 256 + 256; ++d) {
    float wv = wp[(size_t)d * DMODEL];
    a0 += xs[0][d] * wv; a1 += xs[1][d] * wv; a2 += xs[2][d] * wv; a3 += xs[3][d] * wv;
  }
  if (dh == 1) { red[0][tid & 127] = a0; red[1][tid & 127] = a1; red[2][tid & 127] = a2; red[3][tid & 127] = a3; }
  __syncthreads();
  if (dh == 0) {
    a0 += red[0][tid & 127]; a1 += red[1][tid & 127]; a2 += red[2][tid & 127]; a3 += red[3][tid & 127];
    int hh = o >> 6, dd = o & 63;
    float v[4] = {a0, a1, a2, a3};
#pragma unroll
    for (int b = 0; b < NBATCH; ++b)
      Out[(((size_t)b * NHEAD + hh) * out_L + orow) * HDIM + dd] = f2bf(v[b] * scale);
  }
}

// ---------------- global V transpose: Vt[bh][d][kv] = V[bh][kv][d] ----------------
__global__ __launch_bounds__(256) void vtrans(const unsigned short* __restrict__ V,
                                              unsigned short* __restrict__ Vt) {
  __shared__ unsigned short t[64 * 64];
  const int tid = threadIdx.x;
  const int kv0 = blockIdx.x * 64, bh = blockIdx.y;
  const unsigned short* Vhp = V + (size_t)bh * KLEN * HDIM;
  unsigned short* Vtp = Vt + (size_t)bh * HDIM * KLEN;

#pragma unroll
  for (int i = 0; i < 2; ++i) {
    int c = i * 256 + tid;             // 512 chunks of 16B: row = kv-local, c8 = d-chunk
    int row = c >> 3, c8 = c & 7;
    int kvg = kv0 + row; if (kvg > KLEN - 1) kvg = KLEN - 1;
    int4 v4 = *(const int4*)(Vhp + (size_t)kvg * HDIM + c8 * 8);
    *(int4*)&t[row * 64 + ((c8 ^ ((row >> 3) & 7)) * 8)] = v4;
  }
  __syncthreads();
#pragma unroll
  for (int i = 0; i < 2; ++i) {
    int c = i * 256 + tid;             // 512: d row, k8 = kv-chunk
    int d = c >> 3, k8 = c & 7;
    if (kv0 + k8 * 8 <= KLEN - 8) {
      unsigned int wd[4];
#pragma unroll
      for (int jj = 0; jj < 4; ++jj) {
        int ka = k8 * 8 + jj * 2, kb2 = ka + 1;
        unsigned int lo = t[ka  * 64 + (((d >> 3) ^ ((ka  >> 3) & 7)) * 8) + (d & 7)];
        unsigned int hi = t[kb2 * 64 + (((d >> 3) ^ ((kb2 >> 3) & 7)) * 8) + (d & 7)];
        wd[jj] = lo | (hi << 16);
      }
      int4 o; o.x = wd[0]; o.y = wd[1]; o.z = wd[2]; o.w = wd[3];
      *(int4*)(Vtp + (size_t)d * KLEN + kv0 + k8 * 8) = o;
    }
  }
}

// ---------------- flash attention ----------------
// KVB=64, 4 waves (wave w owns q rows q0+w*16..+15), double-buffered direct
// global_load_lds staging with XOR-chunk swizzle (16B chunk c -> c ^ ((c>>3)&7)
// within each 8-chunk row; involution, applied on global source AND LDS read).
// Register footprint kept at R1's proven ~88 level (no reg prefetch arrays) —
// R3/R4 showed the backend pins VGPRs at ~68-72 and spills larger sets (735 MB
// scratch writes). Pipelining comes free via the DMA queue instead.
__global__ __launch_bounds__(256) void attn_kernel(const unsigned short* __restrict__ Qb,
                                                   const unsigned short* __restrict__ Kb,
                                                   const unsigned short* __restrict__ Vtg,
                                                   unsigned short* __restrict__ Att) {
  __shared__ unsigned short Ks[2][64 * 64];   // 8 KB x2, [kv][d] swizzled
  __shared__ unsigned short Vs[2][64 * 64];   // 8 KB x2, [d][kv] swizzled
  __shared__ unsigned short Ps[4][16 * PP];   // 9 KB, per-wave [q][kv]

  const int tid = threadIdx.x;
  const int w = tid >> 6, l = tid & 63;
  const int lg = l >> 4, lr = l & 15;
  const int qb = 32 - (int)blockIdx.x;                 // big blocks first
  const int bh = (int)blockIdx.z * NHEAD + (int)blockIdx.y;
  const int q0 = qb * 64;
  const int base = NXT + q0;
  const int nkb = (base >> 6) + 1;

  const unsigned short* Qh = Qb + (size_t)bh * QLEN * HDIM;
  const unsigned short* Kh = Kb + (size_t)bh * KLEN * HDIM;
  const unsigned short* Vh = Vtg + (size_t)bh * HDIM * KLEN;   // [64][KLEN]

  int qrow = q0 + w * 16 + lr; if (qrow > QLEN - 1) qrow = QLEN - 1;
  const bf16x8 qa0 = *(const bf16x8*)(Qh + (size_t)qrow * HDIM + lg * 8);
  const bf16x8 qa1 = *(const bf16x8*)(Qh + (size_t)qrow * HDIM + 32 + lg * 8);

  f32x4 acc[4];
#pragma unroll
  for (int n = 0; n < 4; ++n) acc[n] = (f32x4){0.f, 0.f, 0.f, 0.f};
  float m_r[4], lsum[4];
#pragma unroll
  for (int r = 0; r < 4; ++r) { m_r[r] = -1e30f; lsum[r] = 0.f; }

  // staging lane geometry: lane l covers dest chunk l of a 64-chunk (1KB) wave call;
  // dest (row r8+rloc, col-chunk l&7) must hold source col-chunk (l&7)^rloc.
  const int rloc = l >> 3;
  const int jsrc = ((l & 7) ^ rloc) * 8;     // source col in elems

#define STAGE(buf, kv0s)                                                            \
  {                                                                                 \
    _Pragma("unroll")                                                               \
    for (int i = 0; i < 2; ++i) {                                                   \
      const int r8 = (w * 2 + i) * 8;                                               \
      int kr = (kv0s) + r8 + rloc; if (kr > KLEN - 1) kr = KLEN - 1;                \
      gload_lds16(Kh + (size_t)kr * HDIM + jsrc, &Ks[buf][r8 * 64]);                \
      int vc = (kv0s) + jsrc; if (vc > KLEN - 8) vc = KLEN - 8;                     \
      gload_lds16(Vh + (size_t)(r8 + rloc) * KLEN + vc, &Vs[buf][r8 * 64]);         \
    }                                                                               \
  }

  STAGE(0, 0)
  __syncthreads();
  int cur = 0;

  for (int kb = 0; kb < nkb; ++kb) {
    if (kb + 1 < nkb) STAGE(cur ^ 1, (kb + 1) * 64)   // lands during this tile's compute

    const unsigned short* Kc = &Ks[cur][0];
    const unsigned short* Vc = &Vs[cur][0];

    // S = Q K^T : 16 q-rows x 64 keys per wave (swizzled reads)
    f32x4 s[4];
#pragma unroll
    for (int n = 0; n < 4; ++n) {
      const int rk = n * 16 + lr;
      const bf16x8 k0 = *(const bf16x8*)&Kc[rk * 64 + ((lg ^ (rk & 7)) * 8)];
      const bf16x8 k1 = *(const bf16x8*)&Kc[rk * 64 + (((4 + lg) ^ (rk & 7)) * 8)];
      s[n] = mfma16(qa0, k0, (f32x4){0.f, 0.f, 0.f, 0.f});
      s[n] = mfma16(qa1, k1, s[n]);
    }

    if (kb == nkb - 1) {                               // causal mask (kv0 == base here)
#pragma unroll
      for (int n = 0; n < 4; ++n) {
        const int colc = n * 16 + lr;
#pragma unroll
        for (int r = 0; r < 4; ++r)
          if (colc > w * 16 + lg * 4 + r) s[n][r] = -1e30f;
      }
    }

    // online softmax: row r lives on 16-lane group
    float rmax[4];
#pragma unroll
    for (int r = 0; r < 4; ++r) {
      float v = fmaxf(fmaxf(s[0][r], s[1][r]), fmaxf(s[2][r], s[3][r]));
      v = fmaxf(v, __shfl_xor(v, 1)); v = fmaxf(v, __shfl_xor(v, 2));
      v = fmaxf(v, __shfl_xor(v, 4)); v = fmaxf(v, __shfl_xor(v, 8));
      rmax[r] = v;
    }
    int grow = (rmax[0] > m_r[0] + 8.f) | (rmax[1] > m_r[1] + 8.f) |
               (rmax[2] > m_r[2] + 8.f) | (rmax[3] > m_r[3] + 8.f);
    if (__any(grow)) {                                 // T13 defer-max
#pragma unroll
      for (int r = 0; r < 4; ++r) {
        float mn = fmaxf(m_r[r], rmax[r]);
        float sc = __expf(m_r[r] - mn);
        lsum[r] *= sc;
#pragma unroll
        for (int n = 0; n < 4; ++n) acc[n][r] *= sc;
        m_r[r] = mn;
      }
    }
    float rsum[4] = {0.f, 0.f, 0.f, 0.f};
#pragma unroll
    for (int n = 0; n < 4; ++n)
#pragma unroll
      for (int r = 0; r < 4; ++r) {
        float p = __expf(s[n][r] - m_r[r]);
        s[n][r] = p; rsum[r] += p;
      }
#pragma unroll
    for (int r = 0; r < 4; ++r) {
      float v = rsum[r];
      v += __shfl_xor(v, 1); v += __shfl_xor(v, 2);
      v += __shfl_xor(v, 4); v += __shfl_xor(v, 8);
      lsum[r] += v;
    }

    // P -> LDS (per-wave), round-half-up to bf16
    unsigned short* Pw = &Ps[w][0];
#pragma unroll
    for (int n = 0; n < 4; ++n)
#pragma unroll
      for (int r = 0; r < 4; ++r) {
        unsigned int u = __float_as_uint(s[n][r]) + 0x8000u;
        Pw[(lg * 4 + r) * PP + n * 16 + lr] = (unsigned short)(u >> 16);
      }
    asm volatile("s_waitcnt lgkmcnt(0)" ::: "memory");
    __builtin_amdgcn_sched_barrier(0);                 // rule #18
    bf16x8 pa[2];
#pragma unroll
    for (int ks = 0; ks < 2; ++ks) pa[ks] = *(const bf16x8*)&Pw[lr * PP + ks * 32 + lg * 8];
#pragma unroll
    for (int n = 0; n < 4; ++n) {
      const int rv = n * 16 + lr;
#pragma unroll
      for (int ks = 0; ks < 2; ++ks) {
        const bf16x8 vv = *(const bf16x8*)&Vc[rv * 64 + (((ks * 4 + lg) ^ (rv & 7)) * 8)];
        acc[n] = mfma16(pa[ks], vv, acc[n]);
      }
    }

    __syncthreads();   // readers of buf[cur] done; next tile's DMA (into cur^1) drained
    cur ^= 1;
  }

  float inv[4];
#pragma unroll
  for (int r = 0; r < 4; ++r) inv[r] = 1.f / lsum[r];
#pragma unroll
  for (int n = 0; n < 4; ++n)
#pragma unroll
    for (int r = 0; r < 4; ++r) {
      int qi = q0 + w * 16 + lg * 4 + r;
      if (qi < QLEN)
        Att[((size_t)blockIdx.z * QLEN + qi) * DMODEL + blockIdx.y * HDIM + n * 16 + lr] =
            f2bf(acc[n][r] * inv[r]);
    }
#undef STAGE
}

// ---------------- output GEMM (unchanged) ----------------
__global__ __launch_bounds__(256) void out_gemm(const unsigned short* __restrict__ A,
                                                const unsigned short* __restrict__ W,
                                                float* __restrict__ Out) {
  __shared__ unsigned short As[128 * 32];
  __shared__ unsigned short Bs[128 * 32];
  const int tid = threadIdx.x;
  const int w = tid >> 6, l = tid & 63;
  const int lg = l >> 4, lr = l & 15;
  const int row0 = blockIdx.x * 128, col0 = blockIdx.y * 128;
  const int wr = (w >> 1) * 64, wc = (w & 1) * 64;

  f32x4 acc[4][4];
#pragma unroll
  for (int m = 0; m < 4; ++m)
#pragma unroll
    for (int n = 0; n < 4; ++n) acc[m][n] = (f32x4){0.f, 0.f, 0.f, 0.f};

  const int sr = w * 16 + (l >> 2);
  const int sc = (l & 3) * 8;

  for (int k0 = 0; k0 < 512; k0 += 32) {
#pragma unroll
    for (int i = 0; i < 2; ++i) {
      const unsigned short* gpa = A + (size_t)(row0 + sr + i * 64) * 512 + k0 + sc;
      gload_lds16(gpa, (char*)As + i * 4096 + w * 1024);
      const unsigned short* gpb = W + (size_t)(col0 + sr + i * 64) * 512 + k0 + sc;
      gload_lds16(gpb, (char*)Bs + i * 4096 + w * 1024);
    }
    __syncthreads();
    bf16x8 av[4], bv[4];
#pragma unroll
    for (int m = 0; m < 4; ++m) av[m] = *(const bf16x8*)&As[(wr + m * 16 + lr) * 32 + lg * 8];
#pragma unroll
    for (int n = 0; n < 4; ++n) bv[n] = *(const bf16x8*)&Bs[(wc + n * 16 + lr) * 32 + lg * 8];
#pragma unroll
    for (int m = 0; m < 4; ++m)
#pragma unroll
      for (int n = 0; n < 4; ++n) acc[m][n] = mfma16(av[m], bv[n], acc[m][n]);
    __syncthreads();
  }

#pragma unroll
  for (int m = 0; m < 4; ++m) {
    int crow = row0 + wr + m * 16 + lg * 4;
#pragma unroll
    for (int n = 0; n < 4; ++n) {
      int ccol = col0 + wc + n * 16 + lr;
#pragma unroll
      for (int r = 0; r < 4; ++r) {
        int cr = crow + r;
        int bb = cr / QLEN, ii = cr - bb * QLEN;
        size_t off = ii < NXT
                       ? ((size_t)bb * NXT + ii) * DMODEL + ccol
                       : (size_t)NBATCH * NXT * DMODEL + ((size_t)bb * NSN + (ii - NXT)) * DMODEL + ccol;
        Out[off] = acc[m][n][r];
      }
    }
  }
}

// ---------------- host launch ----------------
extern "C" void kernel_launch(void* const* d_in, const int* in_sizes, int n_in,
                              void* d_out, int out_size, void* d_ws, size_t ws_size,
                              hipStream_t stream) {
  const float* seq = (const float*)d_in[0];
  const float* nst = (const float*)d_in[2];
  const float* Wq  = (const float*)d_in[5];
  const float* Wk  = (const float*)d_in[6];
  const float* Wv  = (const float*)d_in[7];
  const float* nsq = (const float*)d_in[8];
  const float* nsk = (const float*)d_in[9];
  const float* nsv = (const float*)d_in[10];
  const float* Wo  = (const float*)d_in[11];
  float* out = (float*)d_out;

  // fully disjoint workspace layout (no aliasing)
  char* ws = (char*)d_ws;
  unsigned short* Xbf  = (unsigned short*)(ws);                       // 16,777,216
  unsigned short* Wqb  = (unsigned short*)(ws + 16777216);            // 524,288 x4
  unsigned short* Wkb  = Wqb + 262144;
  unsigned short* Wvb  = Wkb + 262144;
  unsigned short* Wob  = Wvb + 262144;
  unsigned short* Qbuf = (unsigned short*)(ws + 18874368);            // 8,519,680
  unsigned short* Kbuf = (unsigned short*)(ws + 27394048);            // 16,908,288
  unsigned short* Vbuf = (unsigned short*)(ws + 44302336);            // 16,908,288
  unsigned short* Att  = (unsigned short*)(ws + 61210624);            // 8,519,680
  unsigned short* Vtg  = (unsigned short*)(ws + 69730304);            // 16,908,288 -> total 86,638,592
  if (ws_size < 86638592) return;   // insufficient scratch -> visible first-call failure

  cvt_f32_bf16_v4<<<dim3(8192), dim3(256), 0, stream>>>(seq, Xbf, 2097152);
  cvt_w4<<<dim3(256, 4), dim3(256), 0, stream>>>(Wq, Wk, Wv, Wo, Wqb);
  proj_gemm<<<dim3(128, 4), dim3(256), 0, stream>>>(Xbf, Wkb, Kbuf, 12, 0, KLEN, 1.f);
  proj_gemm<<<dim3(128, 4), dim3(256), 0, stream>>>(Xbf, Wvb, Vbuf, 12, 0, KLEN, 1.f);
  proj_gemm<<<dim3(64, 4), dim3(256), 0, stream>>>(Xbf, Wqb, Qbuf, 11, 2048, QLEN, 0.125f);
  ns_proj<<<dim3(4, 32, 3), dim3(256), 0, stream>>>(nst, nsq, nsk, nsv, Qbuf, Kbuf, Vbuf);
  vtrans<<<dim3(65, 32), dim3(256), 0, stream>>>(Vbuf, Vtg);
  attn_kernel<<<dim3(33, 8, 4), dim3(256), 0, stream>>>(Qbuf, Kbuf, Vtg, Att);
  out_gemm<<<dim3(65, 4), dim3(256), 0, stream>>>(Att, Wob, out);
}

// Round 6
// 298.414 us; speedup vs baseline: 1.4853x; 1.0964x over previous
//
#include <hip/hip_runtime.h>

// ---------------- problem constants ----------------
#define NBATCH 4
#define SEQ    4096
#define DMODEL 512
#define NHEAD  8
#define HDIM   64
#define NSN    32
#define NXT    2048
#define QLEN   2080   // NXT + NSN
#define KLEN   4128   // SEQ + NSN

using bf16x8 = __attribute__((ext_vector_type(8))) short;
using f32x4  = __attribute__((ext_vector_type(4))) float;

typedef __attribute__((address_space(1))) unsigned int gu32;
typedef __attribute__((address_space(3))) unsigned int lu32;

// Q projection pre-scale: SCALE * log2(e) — softmax runs in exp2 domain
#define QSCALE 0.18033688f

__device__ __forceinline__ unsigned short f2bf(float f) {
  unsigned int u = __float_as_uint(f);
  u += 0x7FFF + ((u >> 16) & 1);          // RTNE
  return (unsigned short)(u >> 16);
}

__device__ __forceinline__ f32x4 mfma16(bf16x8 a, bf16x8 b, f32x4 c) {
  return __builtin_amdgcn_mfma_f32_16x16x32_bf16(a, b, c, 0, 0, 0);
}

__device__ __forceinline__ void gload_lds16(const void* g, void* lds_base) {
  __builtin_amdgcn_global_load_lds((const gu32*)g, (lu32*)lds_base, 16, 0, 0);
}

// DPP 16-lane reductions (VALU only — replaces ds_swizzle/bpermute shfl_xor)
template <int C>
__device__ __forceinline__ float fmax_dpp(float v) {
  int o = __builtin_amdgcn_update_dpp(0, __float_as_int(v), C, 0xF, 0xF, false);
  return fmaxf(v, __int_as_float(o));
}
template <int C>
__device__ __forceinline__ float fadd_dpp(float v) {
  int o = __builtin_amdgcn_update_dpp(0, __float_as_int(v), C, 0xF, 0xF, false);
  return v + __int_as_float(o);
}
__device__ __forceinline__ float red_max16(float v) {
  v = fmax_dpp<0xB1>(v);   // quad_perm [1,0,3,2]  (xor 1)
  v = fmax_dpp<0x4E>(v);   // quad_perm [2,3,0,1]  (xor 2)
  v = fmax_dpp<0x141>(v);  // row_half_mirror      (xor 4-ish)
  v = fmax_dpp<0x140>(v);  // row_mirror           (xor 8-ish)
  return v;
}
__device__ __forceinline__ float red_sum16(float v) {
  v = fadd_dpp<0xB1>(v);
  v = fadd_dpp<0x4E>(v);
  v = fadd_dpp<0x141>(v);
  v = fadd_dpp<0x140>(v);
  return v;
}

// ---------------- fp32 -> bf16 converts ----------------
__global__ __launch_bounds__(256) void cvt_f32_bf16_v4(const float* __restrict__ src,
                                                       unsigned short* __restrict__ dst, int n4) {
  int i = blockIdx.x * 256 + threadIdx.x;
  if (i >= n4) return;
  float4 v = reinterpret_cast<const float4*>(src)[i];
  ushort4 r;
  r.x = f2bf(v.x); r.y = f2bf(v.y); r.z = f2bf(v.z); r.w = f2bf(v.w);
  reinterpret_cast<ushort4*>(dst)[i] = r;
}

__global__ __launch_bounds__(256) void cvt_w4(const float* __restrict__ a, const float* __restrict__ b,
                                              const float* __restrict__ c, const float* __restrict__ d,
                                              unsigned short* __restrict__ dst) {
  const float* s = blockIdx.y == 0 ? a : blockIdx.y == 1 ? b : blockIdx.y == 2 ? c : d;
  int i = blockIdx.x * 256 + threadIdx.x;   // 65536 float4 per matrix
  float4 v = reinterpret_cast<const float4*>(s)[i];
  ushort4 r;
  r.x = f2bf(v.x); r.y = f2bf(v.y); r.z = f2bf(v.z); r.w = f2bf(v.w);
  reinterpret_cast<ushort4*>(dst)[(size_t)blockIdx.y * 65536 + i] = r;
}

// ---------------- seq projection GEMM (m97 structure, known-good) ----------------
__global__ __launch_bounds__(256) void proj_gemm(const unsigned short* __restrict__ X,
                                                 const unsigned short* __restrict__ W,
                                                 unsigned short* __restrict__ Out,
                                                 int rpb_shift, int row_off, int out_L, float scale) {
  __shared__ unsigned short As[128 * 32];
  __shared__ unsigned short Bs[128 * 32];
  const int tid = threadIdx.x;
  const int w = tid >> 6, l = tid & 63;
  const int lg = l >> 4, lr = l & 15;
  const int row0 = blockIdx.x * 128, col0 = blockIdx.y * 128;
  const int wr = (w >> 1) * 64, wc = (w & 1) * 64;
  const int mask = (1 << rpb_shift) - 1;

  f32x4 acc[4][4];
#pragma unroll
  for (int m = 0; m < 4; ++m)
#pragma unroll
    for (int n = 0; n < 4; ++n) acc[m][n] = (f32x4){0.f, 0.f, 0.f, 0.f};

  const int sr = w * 16 + (l >> 2);
  const int sc = (l & 3) * 8;

  for (int k0 = 0; k0 < 512; k0 += 32) {
#pragma unroll
    for (int i = 0; i < 2; ++i) {
      int gr = row0 + sr + i * 64;
      int xrow = ((gr >> rpb_shift) << 12) + row_off + (gr & mask);
      const unsigned short* gpa = X + (size_t)xrow * 512 + k0 + sc;
      gload_lds16(gpa, (char*)As + i * 4096 + w * 1024);
      const unsigned short* gpb = W + (size_t)(col0 + sr + i * 64) * 512 + k0 + sc;
      gload_lds16(gpb, (char*)Bs + i * 4096 + w * 1024);
    }
    __syncthreads();
    bf16x8 av[4], bv[4];
#pragma unroll
    for (int m = 0; m < 4; ++m) av[m] = *(const bf16x8*)&As[(wr + m * 16 + lr) * 32 + lg * 8];
#pragma unroll
    for (int n = 0; n < 4; ++n) bv[n] = *(const bf16x8*)&Bs[(wc + n * 16 + lr) * 32 + lg * 8];
#pragma unroll
    for (int m = 0; m < 4; ++m)
#pragma unroll
      for (int n = 0; n < 4; ++n) acc[m][n] = mfma16(av[m], bv[n], acc[m][n]);
    __syncthreads();
  }

#pragma unroll
  for (int m = 0; m < 4; ++m) {
    int crow = row0 + wr + m * 16 + lg * 4;
#pragma unroll
    for (int n = 0; n < 4; ++n) {
      int ccol = col0 + wc + n * 16 + lr;
      int hh = ccol >> 6, dd = ccol & 63;
#pragma unroll
      for (int r = 0; r < 4; ++r) {
        int cr = crow + r;
        int bb = cr >> rpb_shift, ii = cr & mask;
        Out[(((size_t)bb * NHEAD + hh) * out_L + ii) * HDIM + dd] = f2bf(acc[m][n][r] * scale);
      }
    }
  }
}

// ---------------- ns projections ----------------
__global__ __launch_bounds__(256) void ns_proj(const float* __restrict__ nst,
                                               const float* __restrict__ Wnq, const float* __restrict__ Wnk,
                                               const float* __restrict__ Wnv,
                                               unsigned short* __restrict__ Qb, unsigned short* __restrict__ Kb,
                                               unsigned short* __restrict__ Vb) {
  const int oc = blockIdx.x, n = blockIdx.y, p = blockIdx.z;
  const float* W = p == 0 ? Wnq : p == 1 ? Wnk : Wnv;
  unsigned short* Out = p == 0 ? Qb : p == 1 ? Kb : Vb;
  const int out_L = p == 0 ? QLEN : KLEN;
  const int orow = p == 0 ? NXT + n : SEQ + n;
  const float scale = p == 0 ? QSCALE : 1.f;

  __shared__ float xs[NBATCH][DMODEL];
  __shared__ float red[NBATCH][128];
  const int tid = threadIdx.x;
  for (int idx = tid; idx < NBATCH * DMODEL; idx += 256)
    xs[idx >> 9][idx & 511] = nst[(size_t)((idx >> 9) * NSN + n) * DMODEL + (idx & 511)];
  __syncthreads();

  const int o = oc * 128 + (tid & 127);
  const int dh = tid >> 7;
  float a0 = 0.f, a1 = 0.f, a2 = 0.f, a3 = 0.f;
  const float* wp = W + (size_t)n * DMODEL * DMODEL + o;
#pragma unroll 8
  for (int d = dh * 256; d < dh * 256 + 256; ++d) {
    float wv = wp[(size_t)d * DMODEL];
    a0 += xs[0][d] * wv; a1 += xs[1][d] * wv; a2 += xs[2][d] * wv; a3 += xs[3][d] * wv;
  }
  if (dh == 1) { red[0][tid & 127] = a0; red[1][tid & 127] = a1; red[2][tid & 127] = a2; red[3][tid & 127] = a3; }
  __syncthreads();
  if (dh == 0) {
    a0 += red[0][tid & 127]; a1 += red[1][tid & 127]; a2 += red[2][tid & 127]; a3 += red[3][tid & 127];
    int hh = o >> 6, dd = o & 63;
    float v[4] = {a0, a1, a2, a3};
#pragma unroll
    for (int b = 0; b < NBATCH; ++b)
      Out[(((size_t)b * NHEAD + hh) * out_L + orow) * HDIM + dd] = f2bf(v[b] * scale);
  }
}

// ---------------- global V transpose: Vt[bh][d][kv] = V[bh][kv][d] ----------------
__global__ __launch_bounds__(256) void vtrans(const unsigned short* __restrict__ V,
                                              unsigned short* __restrict__ Vt) {
  __shared__ unsigned short t[64 * 64];
  const int tid = threadIdx.x;
  const int kv0 = blockIdx.x * 64, bh = blockIdx.y;
  const unsigned short* Vhp = V + (size_t)bh * KLEN * HDIM;
  unsigned short* Vtp = Vt + (size_t)bh * HDIM * KLEN;

#pragma unroll
  for (int i = 0; i < 2; ++i) {
    int c = i * 256 + tid;             // 512 chunks of 16B: row = kv-local, c8 = d-chunk
    int row = c >> 3, c8 = c & 7;
    int kvg = kv0 + row; if (kvg > KLEN - 1) kvg = KLEN - 1;
    int4 v4 = *(const int4*)(Vhp + (size_t)kvg * HDIM + c8 * 8);
    *(int4*)&t[row * 64 + ((c8 ^ ((row >> 3) & 7)) * 8)] = v4;
  }
  __syncthreads();
#pragma unroll
  for (int i = 0; i < 2; ++i) {
    int c = i * 256 + tid;             // 512: d row, k8 = kv-chunk
    int d = c >> 3, k8 = c & 7;
    if (kv0 + k8 * 8 <= KLEN - 8) {
      unsigned int wd[4];
#pragma unroll
      for (int jj = 0; jj < 4; ++jj) {
        int ka = k8 * 8 + jj * 2, kb2 = ka + 1;
        unsigned int lo = t[ka  * 64 + (((d >> 3) ^ ((ka  >> 3) & 7)) * 8) + (d & 7)];
        unsigned int hi = t[kb2 * 64 + (((d >> 3) ^ ((kb2 >> 3) & 7)) * 8) + (d & 7)];
        wd[jj] = lo | (hi << 16);
      }
      int4 o; o.x = wd[0]; o.y = wd[1]; o.z = wd[2]; o.w = wd[3];
      *(int4*)(Vtp + (size_t)d * KLEN + kv0 + k8 * 8) = o;
    }
  }
}

// ---------------- flash attention ----------------
// KVB=64, 4 waves, double-buffered global_load_lds staging (XOR-chunk swizzle).
// R6: DPP-based softmax reductions (no LDS-pipe shfl), exp2-domain softmax
// (log2e folded into Q projection), Ps shrunk+swizzled -> LDS 40960B = 4 blocks/CU.
__global__ __launch_bounds__(256) void attn_kernel(const unsigned short* __restrict__ Qb,
                                                   const unsigned short* __restrict__ Kb,
                                                   const unsigned short* __restrict__ Vtg,
                                                   unsigned short* __restrict__ Att) {
  __shared__ unsigned short Ks[2][64 * 64];   // 8 KB x2, [kv][d] swizzled
  __shared__ unsigned short Vs[2][64 * 64];   // 8 KB x2, [d][kv] swizzled
  __shared__ unsigned short Ps[4][16 * 64];   // 2 KB x4, per-wave [q][kv] swizzled

  const int tid = threadIdx.x;
  const int w = tid >> 6, l = tid & 63;
  const int lg = l >> 4, lr = l & 15;
  const int qb = 32 - (int)blockIdx.x;                 // big blocks first
  const int bh = (int)blockIdx.z * NHEAD + (int)blockIdx.y;
  const int q0 = qb * 64;
  const int base = NXT + q0;
  const int nkb = (base >> 6) + 1;

  const unsigned short* Qh = Qb + (size_t)bh * QLEN * HDIM;
  const unsigned short* Kh = Kb + (size_t)bh * KLEN * HDIM;
  const unsigned short* Vh = Vtg + (size_t)bh * HDIM * KLEN;   // [64][KLEN]

  int qrow = q0 + w * 16 + lr; if (qrow > QLEN - 1) qrow = QLEN - 1;
  const bf16x8 qa0 = *(const bf16x8*)(Qh + (size_t)qrow * HDIM + lg * 8);
  const bf16x8 qa1 = *(const bf16x8*)(Qh + (size_t)qrow * HDIM + 32 + lg * 8);

  f32x4 acc[4];
#pragma unroll
  for (int n = 0; n < 4; ++n) acc[n] = (f32x4){0.f, 0.f, 0.f, 0.f};
  float m_r[4], lsum[4];
#pragma unroll
  for (int r = 0; r < 4; ++r) { m_r[r] = -1e30f; lsum[r] = 0.f; }

  // staging lane geometry (involutive chunk swizzle, rule #21)
  const int rloc = l >> 3;
  const int jsrc = ((l & 7) ^ rloc) * 8;     // source col in elems

#define STAGE(buf, kv0s)                                                            \
  {                                                                                 \
    _Pragma("unroll")                                                               \
    for (int i = 0; i < 2; ++i) {                                                   \
      const int r8 = (w * 2 + i) * 8;                                               \
      int kr = (kv0s) + r8 + rloc; if (kr > KLEN - 1) kr = KLEN - 1;                \
      gload_lds16(Kh + (size_t)kr * HDIM + jsrc, &Ks[buf][r8 * 64]);                \
      int vc = (kv0s) + jsrc; if (vc > KLEN - 8) vc = KLEN - 8;                     \
      gload_lds16(Vh + (size_t)(r8 + rloc) * KLEN + vc, &Vs[buf][r8 * 64]);         \
    }                                                                               \
  }

  STAGE(0, 0)
  __syncthreads();
  int cur = 0;

  for (int kb = 0; kb < nkb; ++kb) {
    if (kb + 1 < nkb) STAGE(cur ^ 1, (kb + 1) * 64)   // lands during this tile's compute

    const unsigned short* Kc = &Ks[cur][0];
    const unsigned short* Vc = &Vs[cur][0];

    // S = Q K^T : 16 q-rows x 64 keys per wave (swizzled reads)
    f32x4 s[4];
#pragma unroll
    for (int n = 0; n < 4; ++n) {
      const int rk = n * 16 + lr;
      const bf16x8 k0 = *(const bf16x8*)&Kc[rk * 64 + ((lg ^ (rk & 7)) * 8)];
      const bf16x8 k1 = *(const bf16x8*)&Kc[rk * 64 + (((4 + lg) ^ (rk & 7)) * 8)];
      s[n] = mfma16(qa0, k0, (f32x4){0.f, 0.f, 0.f, 0.f});
      s[n] = mfma16(qa1, k1, s[n]);
    }

    if (kb == nkb - 1) {                               // causal mask (kv0 == base here)
#pragma unroll
      for (int n = 0; n < 4; ++n) {
        const int colc = n * 16 + lr;
#pragma unroll
        for (int r = 0; r < 4; ++r)
          if (colc > w * 16 + lg * 4 + r) s[n][r] = -1e30f;
      }
    }

    // online softmax (exp2 domain); row r lives on 16-lane group; DPP reductions
    float rmax[4];
#pragma unroll
    for (int r = 0; r < 4; ++r)
      rmax[r] = red_max16(fmaxf(fmaxf(s[0][r], s[1][r]), fmaxf(s[2][r], s[3][r])));
    int grow = (rmax[0] > m_r[0] + 11.5f) | (rmax[1] > m_r[1] + 11.5f) |
               (rmax[2] > m_r[2] + 11.5f) | (rmax[3] > m_r[3] + 11.5f);
    if (__any(grow)) {                                 // T13 defer-max
#pragma unroll
      for (int r = 0; r < 4; ++r) {
        float mn = fmaxf(m_r[r], rmax[r]);
        float sc = exp2f(m_r[r] - mn);
        lsum[r] *= sc;
#pragma unroll
        for (int n = 0; n < 4; ++n) acc[n][r] *= sc;
        m_r[r] = mn;
      }
    }
    float rsum[4];
#pragma unroll
    for (int r = 0; r < 4; ++r) rsum[r] = 0.f;
#pragma unroll
    for (int n = 0; n < 4; ++n)
#pragma unroll
      for (int r = 0; r < 4; ++r) {
        float p = exp2f(s[n][r] - m_r[r]);
        s[n][r] = p; rsum[r] += p;
      }
#pragma unroll
    for (int r = 0; r < 4; ++r) lsum[r] += red_sum16(rsum[r]);

    // P -> LDS (per-wave, swizzled [q][kv]), round-half-up to bf16
    unsigned short* Pw = &Ps[w][0];
#pragma unroll
    for (int n = 0; n < 4; ++n)
#pragma unroll
      for (int r = 0; r < 4; ++r) {
        unsigned int u = __float_as_uint(s[n][r]) + 0x8000u;
        const int q = lg * 4 + r;
        const int kc = n * 2 + (lr >> 3);
        Pw[q * 64 + ((kc ^ (q & 7)) * 8) + (lr & 7)] = (unsigned short)(u >> 16);
      }
    asm volatile("s_waitcnt lgkmcnt(0)" ::: "memory");
    __builtin_amdgcn_sched_barrier(0);                 // rule #18
    bf16x8 pa[2];
#pragma unroll
    for (int ks = 0; ks < 2; ++ks)
      pa[ks] = *(const bf16x8*)&Pw[lr * 64 + (((ks * 4 + lg) ^ (lr & 7)) * 8)];
#pragma unroll
    for (int n = 0; n < 4; ++n) {
      const int rv = n * 16 + lr;
#pragma unroll
      for (int ks = 0; ks < 2; ++ks) {
        const bf16x8 vv = *(const bf16x8*)&Vc[rv * 64 + (((ks * 4 + lg) ^ (rv & 7)) * 8)];
        acc[n] = mfma16(pa[ks], vv, acc[n]);
      }
    }

    __syncthreads();   // readers of buf[cur] done; next tile's DMA (into cur^1) drained
    cur ^= 1;
  }

  float inv[4];
#pragma unroll
  for (int r = 0; r < 4; ++r) inv[r] = 1.f / lsum[r];
#pragma unroll
  for (int n = 0; n < 4; ++n)
#pragma unroll
    for (int r = 0; r < 4; ++r) {
      int qi = q0 + w * 16 + lg * 4 + r;
      if (qi < QLEN)
        Att[((size_t)blockIdx.z * QLEN + qi) * DMODEL + blockIdx.y * HDIM + n * 16 + lr] =
            f2bf(acc[n][r] * inv[r]);
    }
#undef STAGE
}

// ---------------- output GEMM (unchanged) ----------------
__global__ __launch_bounds__(256) void out_gemm(const unsigned short* __restrict__ A,
                                                const unsigned short* __restrict__ W,
                                                float* __restrict__ Out) {
  __shared__ unsigned short As[128 * 32];
  __shared__ unsigned short Bs[128 * 32];
  const int tid = threadIdx.x;
  const int w = tid >> 6, l = tid & 63;
  const int lg = l >> 4, lr = l & 15;
  const int row0 = blockIdx.x * 128, col0 = blockIdx.y * 128;
  const int wr = (w >> 1) * 64, wc = (w & 1) * 64;

  f32x4 acc[4][4];
#pragma unroll
  for (int m = 0; m < 4; ++m)
#pragma unroll
    for (int n = 0; n < 4; ++n) acc[m][n] = (f32x4){0.f, 0.f, 0.f, 0.f};

  const int sr = w * 16 + (l >> 2);
  const int sc = (l & 3) * 8;

  for (int k0 = 0; k0 < 512; k0 += 32) {
#pragma unroll
    for (int i = 0; i < 2; ++i) {
      const unsigned short* gpa = A + (size_t)(row0 + sr + i * 64) * 512 + k0 + sc;
      gload_lds16(gpa, (char*)As + i * 4096 + w * 1024);
      const unsigned short* gpb = W + (size_t)(col0 + sr + i * 64) * 512 + k0 + sc;
      gload_lds16(gpb, (char*)Bs + i * 4096 + w * 1024);
    }
    __syncthreads();
    bf16x8 av[4], bv[4];
#pragma unroll
    for (int m = 0; m < 4; ++m) av[m] = *(const bf16x8*)&As[(wr + m * 16 + lr) * 32 + lg * 8];
#pragma unroll
    for (int n = 0; n < 4; ++n) bv[n] = *(const bf16x8*)&Bs[(wc + n * 16 + lr) * 32 + lg * 8];
#pragma unroll
    for (int m = 0; m < 4; ++m)
#pragma unroll
      for (int n = 0; n < 4; ++n) acc[m][n] = mfma16(av[m], bv[n], acc[m][n]);
    __syncthreads();
  }

#pragma unroll
  for (int m = 0; m < 4; ++m) {
    int crow = row0 + wr + m * 16 + lg * 4;
#pragma unroll
    for (int n = 0; n < 4; ++n) {
      int ccol = col0 + wc + n * 16 + lr;
#pragma unroll
      for (int r = 0; r < 4; ++r) {
        int cr = crow + r;
        int bb = cr / QLEN, ii = cr - bb * QLEN;
        size_t off = ii < NXT
                       ? ((size_t)bb * NXT + ii) * DMODEL + ccol
                       : (size_t)NBATCH * NXT * DMODEL + ((size_t)bb * NSN + (ii - NXT)) * DMODEL + ccol;
        Out[off] = acc[m][n][r];
      }
    }
  }
}

// ---------------- host launch ----------------
extern "C" void kernel_launch(void* const* d_in, const int* in_sizes, int n_in,
                              void* d_out, int out_size, void* d_ws, size_t ws_size,
                              hipStream_t stream) {
  const float* seq = (const float*)d_in[0];
  const float* nst = (const float*)d_in[2];
  const float* Wq  = (const float*)d_in[5];
  const float* Wk  = (const float*)d_in[6];
  const float* Wv  = (const float*)d_in[7];
  const float* nsq = (const float*)d_in[8];
  const float* nsk = (const float*)d_in[9];
  const float* nsv = (const float*)d_in[10];
  const float* Wo  = (const float*)d_in[11];
  float* out = (float*)d_out;

  // fully disjoint workspace layout (no aliasing)
  char* ws = (char*)d_ws;
  unsigned short* Xbf  = (unsigned short*)(ws);                       // 16,777,216
  unsigned short* Wqb  = (unsigned short*)(ws + 16777216);            // 524,288 x4
  unsigned short* Wkb  = Wqb + 262144;
  unsigned short* Wvb  = Wkb + 262144;
  unsigned short* Wob  = Wvb + 262144;
  unsigned short* Qbuf = (unsigned short*)(ws + 18874368);            // 8,519,680
  unsigned short* Kbuf = (unsigned short*)(ws + 27394048);            // 16,908,288
  unsigned short* Vbuf = (unsigned short*)(ws + 44302336);            // 16,908,288
  unsigned short* Att  = (unsigned short*)(ws + 61210624);            // 8,519,680
  unsigned short* Vtg  = (unsigned short*)(ws + 69730304);            // 16,908,288 -> total 86,638,592
  if (ws_size < 86638592) return;   // insufficient scratch -> visible first-call failure

  cvt_f32_bf16_v4<<<dim3(8192), dim3(256), 0, stream>>>(seq, Xbf, 2097152);
  cvt_w4<<<dim3(256, 4), dim3(256), 0, stream>>>(Wq, Wk, Wv, Wo, Wqb);
  proj_gemm<<<dim3(128, 4), dim3(256), 0, stream>>>(Xbf, Wkb, Kbuf, 12, 0, KLEN, 1.f);
  proj_gemm<<<dim3(128, 4), dim3(256), 0, stream>>>(Xbf, Wvb, Vbuf, 12, 0, KLEN, 1.f);
  proj_gemm<<<dim3(64, 4), dim3(256), 0, stream>>>(Xbf, Wqb, Qbuf, 11, 2048, QLEN, QSCALE);
  ns_proj<<<dim3(4, 32, 3), dim3(256), 0, stream>>>(nst, nsq, nsk, nsv, Qbuf, Kbuf, Vbuf);
  vtrans<<<dim3(65, 32), dim3(256), 0, stream>>>(Vbuf, Vtg);
  attn_kernel<<<dim3(33, 8, 4), dim3(256), 0, stream>>>(Qbuf, Kbuf, Vtg, Att);
  out_gemm<<<dim3(65, 4), dim3(256), 0, stream>>>(Att, Wob, out);
}